// Round 13
// baseline (642.524 us; speedup 1.0000x reference)
//
#include <hip/hip_runtime.h>
#include <math.h>

// ---------------- problem constants ----------------
#define B_  64
#define S_  128
#define H_  128
#define D_  300
#define L_  20
#define G4  512                 // 4*H
#define SH  (S_*H_)             // 16384
#define BSH ((size_t)B_*SH)     // 1048576
#define EPSV 1e-8f

typedef __attribute__((ext_vector_type(8))) short bshort8;   // 8 bf16 (4 VGPR)
typedef __attribute__((ext_vector_type(4))) float f32x4;     // MFMA C/D

// monotonic float<->uint mapping for atomicMax on floats (handles negatives)
__device__ __forceinline__ unsigned fmap(float f){
  unsigned u = __float_as_uint(f);
  return (u & 0x80000000u) ? ~u : (u | 0x80000000u);
}
__device__ __forceinline__ float funmap(unsigned u){
  return __uint_as_float((u & 0x80000000u) ? (u & 0x7fffffffu) : ~u);
}
__device__ __forceinline__ float sigmf(float x){ return 1.f/(1.f+expf(-x)); }
// NaN-safe fast activations (__expf; gates here are O(1), err ~1e-6).
// Verified numerically safe: R11/R12 passes with unchanged absmax.
__device__ __forceinline__ float fsigm(float x){ return 1.f/(1.f+__expf(-x)); }
__device__ __forceinline__ float ftanh(float x){ return 1.f - 2.f/(__expf(2.f*x)+1.f); }
__device__ __forceinline__ float dot4(float4 a, float4 b){
  return a.x*b.x + a.y*b.y + a.z*b.z + a.w*b.w;
}
// wave-uniform broadcast of lane k's value (SGPR), no LDS pipe
__device__ __forceinline__ float blane(float v, int k){
  return __int_as_float(__builtin_amdgcn_readlane(__float_as_int(v), k));
}
// fp32 -> bf16 round-to-nearest-even
__device__ __forceinline__ unsigned short f2bf(float f){
  unsigned u = __float_as_uint(f);
  unsigned r = u + 0x7fffu + ((u >> 16) & 1u);
  return (unsigned short)(r >> 16);
}
__device__ __forceinline__ float bf2f(unsigned short us){
  return __uint_as_float(((unsigned)us) << 16);
}
// XOR swizzles: row-major [row][cols], float4-index XOR'd with (row>>3)
__device__ __forceinline__ int swz64(int row, int h){   // 64 cols
  return (row << 6) + ((((h >> 2) ^ ((row >> 3) & 15)) << 2) | (h & 3));
}
__device__ __forceinline__ int swz128(int row, int h){  // 128 cols
  return (row << 7) + ((((h >> 2) ^ ((row >> 3) & 15)) << 2) | (h & 3));
}
// bf16 LDS swizzle: row-major [128 rows][128 h] halfwords; 16B slot XOR row&15
__device__ __forceinline__ int bswz(int row, int slot){  // slot = h>>3
  return (row << 7) + (((slot ^ (row & 15)) << 3));
}
// split fp32 -> (hi,lo) bf16 packs: 8 floats -> 2x int4 (8 bf16 each)
__device__ __forceinline__ void cvt8(float4 a0, float4 a1, int4& hi, int4& lo){
  float v[8] = {a0.x, a0.y, a0.z, a0.w, a1.x, a1.y, a1.z, a1.w};
  unsigned short h[8], l[8];
  #pragma unroll
  for (int i = 0; i < 8; i++) {
    h[i] = f2bf(v[i]);
    float d = v[i] - bf2f(h[i]);
    l[i] = f2bf(d);
  }
  hi = make_int4((unsigned)h[0] | ((unsigned)h[1] << 16), (unsigned)h[2] | ((unsigned)h[3] << 16),
                 (unsigned)h[4] | ((unsigned)h[5] << 16), (unsigned)h[6] | ((unsigned)h[7] << 16));
  lo = make_int4((unsigned)l[0] | ((unsigned)l[1] << 16), (unsigned)l[2] | ((unsigned)l[3] << 16),
                 (unsigned)l[4] | ((unsigned)l[5] << 16), (unsigned)l[6] | ((unsigned)l[7] << 16));
}

// ---------------- embedding gather ----------------
__global__ void k_embed(const float* __restrict__ emb, const int* __restrict__ p,
                        const int* __restrict__ h, float* __restrict__ x1,
                        float* __restrict__ x2)
{
  int row = blockIdx.x;
  const int* idx = blockIdx.y ? h : p;
  float* x = blockIdx.y ? x2 : x1;
  int tok = idx[row];
  const float* src = emb + (size_t)tok * D_;
  float* dst = x + (size_t)row * D_;
  for (int d = threadIdx.x; d < D_; d += blockDim.x) dst[d] = src[d];
}

// ---------------- GEMM (split-bf16 MFMA): C = A(M,K) * W(N,K)^T + bias ----
// fp32 emulated as hi+lo bf16; C = Ah*Wh + Ah*Wl + Al*Wh (lo*lo dropped,
// rel err ~2^-17). 128x128 tile, 8 waves as 4(M)x2(N) grid of 16x16 MFMA
// tiles per wave, BK=32.
template<int K>
__global__ __launch_bounds__(512, 1) void gemm_abt(
    const float* __restrict__ A0, const float* __restrict__ A1,
    const float* __restrict__ W0, const float* __restrict__ W1,
    const float* __restrict__ b0, const float* __restrict__ b1,
    float* __restrict__ Cbase, int M, int N)
{
  int q = blockIdx.z;
  const float* A = (q >> 1) ? A1 : A0;
  const float* W = (q & 1) ? W1 : W0;
  const float* bias = (q & 1) ? b1 : b0;
  float* Cm = Cbase + (size_t)q * M * N;

  __shared__ __align__(16) short AsH[128 * 32];
  __shared__ __align__(16) short AsL[128 * 32];
  __shared__ __align__(16) short WsH[128 * 32];
  __shared__ __align__(16) short WsL[128 * 32];

  int t = threadIdx.x;
  int w = t >> 6, lane = t & 63;
  int r = lane & 15, g = lane >> 4;
  int m0 = blockIdx.x * 128, n0 = blockIdx.y * 128;
  int mbase = (w & 1) * 64;        // 4 m-tiles of 16
  int nbase = (w >> 1) * 32;       // 2 n-tiles of 16

  f32x4 acc[4][2];
  #pragma unroll
  for (int i = 0; i < 4; i++)
    #pragma unroll
    for (int j = 0; j < 2; j++) acc[i][j] = (f32x4){0.f, 0.f, 0.f, 0.f};

  int srow = t >> 2, skc = t & 3;                     // staging: row, k-chunk
  int soff = srow * 32 + ((skc ^ ((srow >> 1) & 3)) << 3);

  #pragma unroll 1
  for (int k0 = 0; k0 < K; k0 += 32) {
    {
      int gk = k0 + (skc << 3);
      float4 z = make_float4(0.f, 0.f, 0.f, 0.f);
      float4 a0v = z, a1v = z, w0v = z, w1v = z;
      if (gk < K) {
        a0v = *(const float4*)&A[(size_t)(m0 + srow) * K + gk];
        w0v = *(const float4*)&W[(size_t)(n0 + srow) * K + gk];
      }
      if (gk + 4 < K) {
        a1v = *(const float4*)&A[(size_t)(m0 + srow) * K + gk + 4];
        w1v = *(const float4*)&W[(size_t)(n0 + srow) * K + gk + 4];
      }
      int4 hi, lo;
      cvt8(a0v, a1v, hi, lo);
      *(int4*)&AsH[soff] = hi; *(int4*)&AsL[soff] = lo;
      cvt8(w0v, w1v, hi, lo);
      *(int4*)&WsH[soff] = hi; *(int4*)&WsL[soff] = lo;
    }
    __syncthreads();
    bshort8 ah[4], al[4], bh[2], bl[2];
    #pragma unroll
    for (int i = 0; i < 4; i++) {
      int R = mbase + i * 16 + r;
      int off = R * 32 + ((g ^ ((R >> 1) & 3)) << 3);
      ah[i] = *(const bshort8*)&AsH[off];
      al[i] = *(const bshort8*)&AsL[off];
    }
    #pragma unroll
    for (int j = 0; j < 2; j++) {
      int R = nbase + j * 16 + r;
      int off = R * 32 + ((g ^ ((R >> 1) & 3)) << 3);
      bh[j] = *(const bshort8*)&WsH[off];
      bl[j] = *(const bshort8*)&WsL[off];
    }
    #pragma unroll
    for (int i = 0; i < 4; i++)
      #pragma unroll
      for (int j = 0; j < 2; j++) {
        acc[i][j] = __builtin_amdgcn_mfma_f32_16x16x32_bf16(ah[i], bh[j], acc[i][j], 0, 0, 0);
        acc[i][j] = __builtin_amdgcn_mfma_f32_16x16x32_bf16(ah[i], bl[j], acc[i][j], 0, 0, 0);
        acc[i][j] = __builtin_amdgcn_mfma_f32_16x16x32_bf16(al[i], bh[j], acc[i][j], 0, 0, 0);
      }
    __syncthreads();
  }
  // epilogue: C/D layout col=lane&15, row=(lane>>4)*4+reg (HW-verified)
  #pragma unroll
  for (int j = 0; j < 2; j++) {
    int gcol = n0 + nbase + j * 16 + r;
    float bv = bias[gcol];
    #pragma unroll
    for (int i = 0; i < 4; i++) {
      #pragma unroll
      for (int rg = 0; rg < 4; rg++) {
        int grow = m0 + mbase + i * 16 + g * 4 + rg;
        Cm[(size_t)grow * N + gcol] = acc[i][j][rg] + bv;
      }
    }
  }
}

// ---------------- LSTM scan ----------------
// R13 = R10's verified structure (gate-pair float2 -> half the readlanes;
// parity double-buffered gsm -> ONE barrier/step; redundant per-wave
// activations with c/h in registers) + R12's verified FAST activations.
// R10 lost only because its redundant activations used library expf/tanhf
// (~155 instr/wave/step on all 8 waves); fsigm/ftanh cut that to ~27.
__global__ __launch_bounds__(512, 1) void k_lstm(const float* __restrict__ xg,
    const float* __restrict__ whhF, const float* __restrict__ whhB,
    float* __restrict__ hs)
{
  int b = blockIdx.x, q = blockIdx.y, dir = q & 1;
  const float* whh = dir ? whhB : whhF;
  const float* xgq = xg + ((size_t)(q * B_ + b)) * (S_ * G4);
  float* out = hs + ((size_t)(q * B_ + b)) * SH;
  int t = threadIdx.x;
  int j = t & 255;                 // gate pair (j, j+256)
  int kh = t >> 8;                 // k-half (wave-uniform: waves 0-3 / 4-7)
  int lane = t & 63;
  int wvid = t >> 6;
  int hidx = kh * 64 + lane;       // the h/c index this thread maintains

  float2 w2[64];                   // w2[k] = (whh[j][kh*64+k], whh[j+256][kh*64+k])
  {
    const float* wr0 = whh + (size_t)j * 128 + kh * 64;
    const float* wr1 = whh + (size_t)(j + 256) * 128 + kh * 64;
    #pragma unroll
    for (int k = 0; k < 64; k += 4) {
      float4 v0 = *(const float4*)(wr0 + k);
      float4 v1 = *(const float4*)(wr1 + k);
      w2[k]     = make_float2(v0.x, v1.x);
      w2[k + 1] = make_float2(v0.y, v1.y);
      w2[k + 2] = make_float2(v0.z, v1.z);
      w2[k + 3] = make_float2(v0.w, v1.w);
    }
  }
  __shared__ float gsm[2][2][512];  // [step parity][khalf][gate]

  float creg = 0.f, hreg = 0.f;
  float xn0 = 0.f, xn1 = 0.f;
  if (kh == 0) {
    int t0 = dir ? (S_ - 1) : 0;
    xn0 = xgq[(size_t)t0 * G4 + j];
    xn1 = xgq[(size_t)t0 * G4 + j + 256];
  }

  for (int st = 0; st < S_; st++) {
    int tt = dir ? (S_ - 1 - st) : st;
    float x0 = xn0, x1 = xn1;
    if (kh == 0) {                  // wave-uniform branch: prefetch next step
      int stn = (st + 1 < S_) ? st + 1 : st;
      int ttn = dir ? (S_ - 1 - stn) : stn;
      xn0 = xgq[(size_t)ttn * G4 + j];
      xn1 = xgq[(size_t)ttn * G4 + j + 256];
    }
    // dot: 4 chains x 2 gates; each blane feeds two FMAs
    float a0x = (kh == 0) ? x0 : 0.f, a0y = (kh == 0) ? x1 : 0.f;
    float a1x = 0.f, a1y = 0.f, a2x = 0.f, a2y = 0.f, a3x = 0.f, a3y = 0.f;
    #pragma unroll
    for (int k = 0; k < 64; k += 4) {
      float s0 = blane(hreg, k);
      float s1 = blane(hreg, k + 1);
      float s2 = blane(hreg, k + 2);
      float s3 = blane(hreg, k + 3);
      a0x += w2[k].x * s0;     a0y += w2[k].y * s0;
      a1x += w2[k + 1].x * s1; a1y += w2[k + 1].y * s1;
      a2x += w2[k + 2].x * s2; a2y += w2[k + 2].y * s2;
      a3x += w2[k + 3].x * s3; a3y += w2[k + 3].y * s3;
    }
    int par = st & 1;
    gsm[par][kh][j]       = (a0x + a1x) + (a2x + a3x);
    gsm[par][kh][j + 256] = (a0y + a1y) + (a2y + a3y);
    __syncthreads();
    // every thread computes its own lane's activation from the partials
    float gi = gsm[par][0][hidx]       + gsm[par][1][hidx];
    float gf = gsm[par][0][128 + hidx] + gsm[par][1][128 + hidx];
    float gg = gsm[par][0][256 + hidx] + gsm[par][1][256 + hidx];
    float go = gsm[par][0][384 + hidx] + gsm[par][1][384 + hidx];
    float ig = fsigm(gi);
    float fg = fsigm(gf);
    float gv = ftanh(gg);
    float og = fsigm(go);
    creg = fg * creg + ig * gv;
    hreg = og * ftanh(creg);
    if (wvid == 0 || wvid == 4)          // one redundant copy writes out
      out[(size_t)tt * H_ + hidx] = hreg;
    // no second barrier: parity double-buffer makes the WAR safe (a wave's
    // overwrite of parity p at step st+2 is after barrier(st+1), which is
    // after every wave's parity-p reads at step st).
  }
}

// ---------------- full matching ----------------
__global__ __launch_bounds__(256) void k_full(const float* __restrict__ C,
    const float* __restrict__ w1, const float* __restrict__ w2,
    float* __restrict__ ag1, float* __restrict__ ag2)
{
  int b = blockIdx.x, q = blockIdx.y, dir = q & 1;
  const float* p1  = C + (size_t)q * BSH + (size_t)b * SH;
  const float* p2l = C + (size_t)((q + 2) & 3) * BSH + (size_t)b * SH + (size_t)(S_ - 1) * H_;
  const float* w = dir ? w2 : w1;
  float* out = (q < 2 ? ag1 : ag2) + (size_t)b * S_ * 160;

  __shared__ float p1s[SH];
  __shared__ float ws2[H_][L_];
  __shared__ float p2s[H_];
  __shared__ float n2s[L_];
  int t = threadIdx.x;
  for (int i = t; i < SH; i += 256) p1s[i] = p1[i];
  for (int i = t; i < H_ * L_; i += 256) { float v = w[i]; ws2[i / L_][i % L_] = v * v; }
  if (t < H_) p2s[t] = p2l[t];
  __syncthreads();
  if (t < L_) {
    float s = 0.f;
    for (int hh = 0; hh < H_; hh++) { float v = p2s[hh]; s += v * v * ws2[hh][t]; }
    n2s[t] = sqrtf(s);
  }
  __syncthreads();
  for (int i = t; i < S_ * L_; i += 256) {
    int s = i / L_, l = i % L_;
    const float* pr = p1s + s * H_;
    float dot = 0.f, n1 = 0.f;
    for (int hh = 0; hh < H_; hh++) {
      float a = pr[hh], ww = ws2[hh][l];
      dot += a * p2s[hh] * ww;
      n1 += a * a * ww;
    }
    n1 = sqrtf(n1);
    out[(size_t)s * 160 + dir * L_ + l] = dot / (fmaxf(n1, EPSV) * fmaxf(n2s[l], EPSV));
  }
}

// ---------------- maxpool matching (bf16 MFMA) ----------------
__global__ __launch_bounds__(512, 1) void k_maxpool(const float* __restrict__ C,
    const float* __restrict__ w3, const float* __restrict__ w4,
    float* __restrict__ ag1, float* __restrict__ ag2)
{
  int b = blockIdx.x, dir = blockIdx.y, lh = blockIdx.z;
  const float* p1 = C + (size_t)(0 + dir) * BSH + (size_t)b * SH;
  const float* p2 = C + (size_t)(2 + dir) * BSH + (size_t)b * SH;
  const float* w = dir ? w4 : w3;

  __shared__ __align__(16) short P1b[128 * 128];
  __shared__ __align__(16) short P2b[128 * 128];
  __shared__ __align__(16) short Ab[128 * 128];
  __shared__ float w2s[128 * 10];
  __shared__ float n1s[128], n2s[128];
  __shared__ unsigned mx2u[128];

  int t = threadIdx.x;
  int wv = t >> 6, lane = t & 63;
  int g = lane >> 4, col = lane & 15;

  for (int i = t; i < 8192; i += 512) {
    int row = i >> 6, hp = i & 63;
    int phys = bswz(row, hp >> 2) + ((hp & 3) << 1);
    float2 v1 = *(const float2*)&p1[(row << 7) + (hp << 1)];
    float2 v2 = *(const float2*)&p2[(row << 7) + (hp << 1)];
    *(unsigned*)&P1b[phys] = (unsigned)f2bf(v1.x) | ((unsigned)f2bf(v1.y) << 16);
    *(unsigned*)&P2b[phys] = (unsigned)f2bf(v2.x) | ((unsigned)f2bf(v2.y) << 16);
  }
  for (int i = t; i < 128 * 10; i += 512) {
    int hh = i / 10, lq = i % 10;
    float wv_ = w[hh * L_ + lh * 10 + lq];
    w2s[i] = wv_ * wv_;
  }
  __syncthreads();

  #pragma unroll 1
  for (int lq = 0; lq < 10; lq++) {
    int lout = lh * 10 + lq;
    for (int i = t; i < 8192; i += 512) {
      int row = i >> 6, hp = i & 63;
      int phys = bswz(row, hp >> 2) + ((hp & 3) << 1);
      unsigned u = *(const unsigned*)&P1b[phys];
      float lo = bf2f((unsigned short)(u & 0xffffu)) * w2s[(hp << 1) * 10 + lq];
      float hi = bf2f((unsigned short)(u >> 16))     * w2s[((hp << 1) + 1) * 10 + lq];
      *(unsigned*)&Ab[phys] = (unsigned)f2bf(lo) | ((unsigned)f2bf(hi) << 16);
    }
    {
      int s = t >> 2, part = t & 3;
      float s1 = 0.f, s2 = 0.f;
      #pragma unroll 1
      for (int hp = part * 16; hp < part * 16 + 16; hp++) {
        int phys = bswz(s, hp >> 2) + ((hp & 3) << 1);
        unsigned u1 = *(const unsigned*)&P1b[phys];
        unsigned u2 = *(const unsigned*)&P2b[phys];
        float wlo = w2s[(hp << 1) * 10 + lq];
        float whi = w2s[((hp << 1) + 1) * 10 + lq];
        float a = bf2f((unsigned short)(u1 & 0xffffu)), bb = bf2f((unsigned short)(u1 >> 16));
        float c2 = bf2f((unsigned short)(u2 & 0xffffu)), d2 = bf2f((unsigned short)(u2 >> 16));
        s1 += a * a * wlo + bb * bb * whi;
        s2 += c2 * c2 * wlo + d2 * d2 * whi;
      }
      s1 += __shfl_xor(s1, 1, 64); s1 += __shfl_xor(s1, 2, 64);
      s2 += __shfl_xor(s2, 1, 64); s2 += __shfl_xor(s2, 2, 64);
      if (part == 0) { n1s[s] = sqrtf(s1); n2s[s] = sqrtf(s2); }
    }
    if (t < 128) mx2u[t] = fmap(-3.4e38f);
    __syncthreads();

    {
      int mrow = (wv << 4) + col;
      f32x4 acc0 = {0,0,0,0}, acc1 = {0,0,0,0}, acc2 = {0,0,0,0}, acc3 = {0,0,0,0};
      f32x4 acc4 = {0,0,0,0}, acc5 = {0,0,0,0}, acc6 = {0,0,0,0}, acc7 = {0,0,0,0};
      #pragma unroll 1
      for (int k0 = 0; k0 < 128; k0 += 32) {
        int slot = ((k0 >> 3) + g) ^ col;
        bshort8 av = *(const bshort8*)&Ab[(mrow << 7) + (slot << 3)];
        bshort8 bv0 = *(const bshort8*)&P2b[((0 << 4) + col << 7) + (slot << 3)];
        bshort8 bv1 = *(const bshort8*)&P2b[(((1 << 4) + col) << 7) + (slot << 3)];
        bshort8 bv2 = *(const bshort8*)&P2b[(((2 << 4) + col) << 7) + (slot << 3)];
        bshort8 bv3 = *(const bshort8*)&P2b[(((3 << 4) + col) << 7) + (slot << 3)];
        bshort8 bv4 = *(const bshort8*)&P2b[(((4 << 4) + col) << 7) + (slot << 3)];
        bshort8 bv5 = *(const bshort8*)&P2b[(((5 << 4) + col) << 7) + (slot << 3)];
        bshort8 bv6 = *(const bshort8*)&P2b[(((6 << 4) + col) << 7) + (slot << 3)];
        bshort8 bv7 = *(const bshort8*)&P2b[(((7 << 4) + col) << 7) + (slot << 3)];
        acc0 = __builtin_amdgcn_mfma_f32_16x16x32_bf16(av, bv0, acc0, 0, 0, 0);
        acc1 = __builtin_amdgcn_mfma_f32_16x16x32_bf16(av, bv1, acc1, 0, 0, 0);
        acc2 = __builtin_amdgcn_mfma_f32_16x16x32_bf16(av, bv2, acc2, 0, 0, 0);
        acc3 = __builtin_amdgcn_mfma_f32_16x16x32_bf16(av, bv3, acc3, 0, 0, 0);
        acc4 = __builtin_amdgcn_mfma_f32_16x16x32_bf16(av, bv4, acc4, 0, 0, 0);
        acc5 = __builtin_amdgcn_mfma_f32_16x16x32_bf16(av, bv5, acc5, 0, 0, 0);
        acc6 = __builtin_amdgcn_mfma_f32_16x16x32_bf16(av, bv6, acc6, 0, 0, 0);
        acc7 = __builtin_amdgcn_mfma_f32_16x16x32_bf16(av, bv7, acc7, 0, 0, 0);
      }
      float n1v[4];
      #pragma unroll
      for (int r = 0; r < 4; r++) n1v[r] = n1s[(wv << 4) + (g << 2) + r];
      float rm[4] = {-3.4e38f, -3.4e38f, -3.4e38f, -3.4e38f};
      float cm[8];
      f32x4 accs[8] = {acc0, acc1, acc2, acc3, acc4, acc5, acc6, acc7};
      #pragma unroll
      for (int c = 0; c < 8; c++) {
        float n2v = n2s[(c << 4) + col];
        float cmx = -3.4e38f;
        #pragma unroll
        for (int r = 0; r < 4; r++) {
          float deno = n1v[r] * n2v;
          float cs = accs[c][r] / (deno > EPSV ? deno : EPSV);
          rm[r] = fmaxf(rm[r], cs);
          cmx = fmaxf(cmx, cs);
        }
        cm[c] = cmx;
      }
      #pragma unroll
      for (int m = 1; m < 16; m <<= 1)
        #pragma unroll
        for (int r = 0; r < 4; r++) rm[r] = fmaxf(rm[r], __shfl_xor(rm[r], m, 64));
      if (col == 0) {
        #pragma unroll
        for (int r = 0; r < 4; r++) {
          int srow = (wv << 4) + (g << 2) + r;
          ag1[(size_t)b * S_ * 160 + (size_t)srow * 160 + 40 + dir * L_ + lout] = rm[r];
        }
      }
      #pragma unroll
      for (int c = 0; c < 8; c++) {
        cm[c] = fmaxf(cm[c], __shfl_xor(cm[c], 16, 64));
        cm[c] = fmaxf(cm[c], __shfl_xor(cm[c], 32, 64));
      }
      if (lane < 16) {
        #pragma unroll
        for (int c = 0; c < 8; c++) atomicMax(&mx2u[(c << 4) + lane], fmap(cm[c]));
      }
    }
    __syncthreads();
    if (t < 128)
      ag2[(size_t)b * S_ * 160 + (size_t)t * 160 + 40 + dir * L_ + lout] = funmap(mx2u[t]);
    __syncthreads();
  }
}

// ---------------- alpha (plain cosine matrix) ----------------
__global__ __launch_bounds__(256, 1) void k_alpha(const float* __restrict__ C,
                                                  float* __restrict__ alpha)
{
  int b = blockIdx.x, dir = blockIdx.y;
  const float* p1 = C + (size_t)(0 + dir) * BSH + (size_t)b * SH;
  const float* p2 = C + (size_t)(2 + dir) * BSH + (size_t)b * SH;
  __shared__ __align__(16) float a1[128 * 64];
  __shared__ __align__(16) float a2[128 * 64];
  __shared__ float n1p[128], n2p[128];
  int t = threadIdx.x, tx = t & 15, ty = t >> 4;
  float acc[8][8] = {};

  for (int pass = 0; pass < 2; pass++) {
    int h0 = pass << 6;
    for (int i = t; i < 128 * 64; i += 256) {
      int row = i >> 6, hh = i & 63;
      int off = swz64(row, hh);
      a1[off] = p1[(size_t)row * H_ + h0 + hh];
      a2[off] = p2[(size_t)row * H_ + h0 + hh];
    }
    __syncthreads();
    {
      int r = t & 127;
      const float* a = (t < 128) ? a1 : a2;
      float s = 0.f;
      #pragma unroll 1
      for (int f = 0; f < 16; f++) {
        float4 v = *(const float4*)&a[(r << 6) + ((f ^ ((r >> 3) & 15)) << 2)];
        s += dot4(v, v);
      }
      float* np = (t < 128) ? n1p : n2p;
      if (pass == 0) np[r] = s; else np[r] += s;
    }
    #pragma unroll 1
    for (int f = 0; f < 16; f++) {
      int cx = ((f ^ ty) << 2);
      int cy = ((f ^ tx) << 2);
      float4 x[8], y[8];
      #pragma unroll
      for (int i = 0; i < 8; i++) x[i] = *(const float4*)&a1[((8 * ty + i) << 6) + cx];
      #pragma unroll
      for (int j = 0; j < 8; j++) y[j] = *(const float4*)&a2[((8 * tx + j) << 6) + cy];
      #pragma unroll
      for (int i = 0; i < 8; i++)
        #pragma unroll
        for (int j = 0; j < 8; j++) acc[i][j] += dot4(x[i], y[j]);
    }
    __syncthreads();
  }
  float inv1[8], inv2[8];
  #pragma unroll
  for (int i = 0; i < 8; i++) inv1[i] = 1.f / fmaxf(sqrtf(n1p[8 * ty + i]), EPSV);
  #pragma unroll
  for (int j = 0; j < 8; j++) inv2[j] = 1.f / fmaxf(sqrtf(n2p[8 * tx + j]), EPSV);
  float* outp = alpha + ((size_t)dir * B_ + b) * SH;
  #pragma unroll
  for (int i = 0; i < 8; i++) {
    int ss = 8 * ty + i;
    float s1 = inv1[i];
    float4 o0 = make_float4(acc[i][0] * s1 * inv2[0], acc[i][1] * s1 * inv2[1],
                            acc[i][2] * s1 * inv2[2], acc[i][3] * s1 * inv2[3]);
    float4 o1 = make_float4(acc[i][4] * s1 * inv2[4], acc[i][5] * s1 * inv2[5],
                            acc[i][6] * s1 * inv2[6], acc[i][7] * s1 * inv2[7]);
    *(float4*)&outp[(size_t)ss * S_ + 8 * tx] = o0;
    *(float4*)&outp[(size_t)ss * S_ + 8 * tx + 4] = o1;
  }
}

// ---------------- attentive matching ----------------
__global__ __launch_bounds__(256, 1) void k_att(const float* __restrict__ C,
    const float* __restrict__ alpha,
    const float* __restrict__ w5, const float* __restrict__ w6,
    const float* __restrict__ w7, const float* __restrict__ w8,
    float* __restrict__ ag1, float* __restrict__ ag2)
{
  int b = blockIdx.x, q = blockIdx.y, dir = q & 1;
  const float* p1  = C + (size_t)q * BSH + (size_t)b * SH;
  const float* m2g = C + (size_t)((q + 2) & 3) * BSH + (size_t)b * SH;
  const float* wa = dir ? w6 : w5;
  const float* wm = dir ? w8 : w7;
  const float* ain = alpha + ((size_t)dir * B_ + b) * SH;
  float* out = (q < 2 ? ag1 : ag2) + (size_t)b * S_ * 160;
  bool tr = (q >= 2);

  __shared__ __align__(16) float A[128 * 128];
  __shared__ __align__(16) float M2T[128 * 128];
  __shared__ __align__(16) float waT[20 * 128];
  __shared__ __align__(16) float wmT[20 * 128];
  __shared__ float rowsum[128];
  __shared__ int   midx[128];
  int t = threadIdx.x, tx = t & 15, ty = t >> 4;

  for (int i = t; i < SH; i += 256) {
    int r = i >> 7, c = i & 127;
    float av = ain[i];
    if (tr) A[swz128(c, r)] = av; else A[swz128(r, c)] = av;
    M2T[swz128(c, r)] = m2g[i];
  }
  for (int i = t; i < H_ * L_; i += 256) {
    int hh = i / L_, l = i % L_;
    float v = wa[i]; waT[l * 128 + hh] = v * v;
    float u = wm[i]; wmT[l * 128 + hh] = u * u;
  }
  __syncthreads();

  if (t < 128) {
    float sum = 0.f, best = -3.4e38f; int bi = 0;
    #pragma unroll 1
    for (int f = 0; f < 32; f++) {
      float4 v = *(const float4*)&A[(t << 7) + (((f ^ ((t >> 3) & 15)) & 31) << 2)];
      sum += v.x + v.y + v.z + v.w;
      int k = f << 2;
      if (v.x > best) { best = v.x; bi = k; }
      if (v.y > best) { best = v.y; bi = k + 1; }
      if (v.z > best) { best = v.z; bi = k + 2; }
      if (v.w > best) { best = v.w; bi = k + 3; }
    }
    rowsum[t] = sum; midx[t] = bi;
  }
  __syncthreads();

  float acc[8][8] = {};
  #pragma unroll 1
  for (int f = 0; f < 32; f++) {
    int cx = (((f ^ ty) & 31) << 2);
    int cy = (((f ^ tx) & 31) << 2);
    float4 x[8], y[8];
    #pragma unroll
    for (int i = 0; i < 8; i++) x[i] = *(const float4*)&A[((8 * ty + i) << 7) + cx];
    #pragma unroll
    for (int j = 0; j < 8; j++) y[j] = *(const float4*)&M2T[((8 * tx + j) << 7) + cy];
    #pragma unroll
    for (int i = 0; i < 8; i++)
      #pragma unroll
      for (int j = 0; j < 8; j++) acc[i][j] += dot4(x[i], y[j]);
  }
  __syncthreads();
  {
    float rinv[8];
    #pragma unroll
    for (int i = 0; i < 8; i++) rinv[i] = 1.f / rowsum[8 * ty + i];
    #pragma unroll
    for (int i = 0; i < 8; i++) {
      int row = 8 * ty + i;
      int f0 = (2 * tx) ^ ((row >> 3) & 15);
      int f1 = (2 * tx + 1) ^ ((row >> 3) & 15);
      float4 o0 = make_float4(acc[i][0] * rinv[i], acc[i][1] * rinv[i],
                              acc[i][2] * rinv[i], acc[i][3] * rinv[i]);
      float4 o1 = make_float4(acc[i][4] * rinv[i], acc[i][5] * rinv[i],
                              acc[i][6] * rinv[i], acc[i][7] * rinv[i]);
      *(float4*)&A[(row << 7) + (f0 << 2)] = o0;
      *(float4*)&A[(row << 7) + (f1 << 2)] = o1;
    }
  }
  __syncthreads();

  {
    int s = t >> 1, l0 = (t & 1) * 10;
    int mi = midx[s];
    const float* m2r = m2g + (size_t)mi * H_;
    const float* p1r = p1 + (size_t)s * H_;
    float dA[10] = {}, nA[10] = {}, bA[10] = {};
    float dM[10] = {}, nM[10] = {}, bM[10] = {};
    #pragma unroll 1
    for (int f = 0; f < 32; f++) {
      float4 pv = *(const float4*)&p1r[f << 2];
      float4 mv = *(const float4*)&m2r[f << 2];
      float4 av = *(const float4*)&A[(s << 7) + (((f ^ ((s >> 3) & 15)) & 31) << 2)];
      float4 ap = make_float4(av.x*pv.x, av.y*pv.y, av.z*pv.z, av.w*pv.w);
      float4 a2 = make_float4(av.x*av.x, av.y*av.y, av.z*av.z, av.w*av.w);
      float4 p2 = make_float4(pv.x*pv.x, pv.y*pv.y, pv.z*pv.z, pv.w*pv.w);
      float4 mp = make_float4(mv.x*pv.x, mv.y*pv.y, mv.z*pv.z, mv.w*pv.w);
      float4 m2 = make_float4(mv.x*mv.x, mv.y*mv.y, mv.z*mv.z, mv.w*mv.w);
      #pragma unroll
      for (int l = 0; l < 10; l++) {
        float4 wv = *(const float4*)&waT[(l0 + l) * 128 + (f << 2)];
        dA[l] += dot4(ap, wv); nA[l] += dot4(a2, wv); bA[l] += dot4(p2, wv);
        float4 uv = *(const float4*)&wmT[(l0 + l) * 128 + (f << 2)];
        dM[l] += dot4(mp, uv); nM[l] += dot4(m2, uv); bM[l] += dot4(p2, uv);
      }
    }
    #pragma unroll
    for (int l = 0; l < 10; l++) {
      int ll = l0 + l;
      out[(size_t)s * 160 + 80  + dir * L_ + ll] =
          dA[l] / (fmaxf(sqrtf(nA[l]), EPSV) * fmaxf(sqrtf(bA[l]), EPSV));
      out[(size_t)s * 160 + 120 + dir * L_ + ll] =
          dM[l] / (fmaxf(sqrtf(nM[l]), EPSV) * fmaxf(sqrtf(bM[l]), EPSV));
    }
  }
}

// ---------------- final MLP ----------------
__global__ __launch_bounds__(256) void k_final(const float* __restrict__ Cc,
    const float* __restrict__ pW1, const float* __restrict__ pb1,
    const float* __restrict__ pW2, const float* __restrict__ pb2,
    float* __restrict__ out)
{
  int b = blockIdx.x, t = threadIdx.x;
  __shared__ float cat[512];
  __shared__ float hid[256];
  if (t < 128) {
    cat[t]       = Cc[(size_t)(0 * B_ + b) * SH + (size_t)(S_ - 1) * H_ + t];
    cat[128 + t] = Cc[(size_t)(1 * B_ + b) * SH + (size_t)(S_ - 1) * H_ + t];
    cat[256 + t] = Cc[(size_t)(2 * B_ + b) * SH + (size_t)(S_ - 1) * H_ + t];
    cat[384 + t] = Cc[(size_t)(3 * B_ + b) * SH + (size_t)(S_ - 1) * H_ + t];
  }
  __syncthreads();
  float a = pb1[t];
  for (int k = 0; k < 512; k++) a += cat[k] * pW1[(size_t)t * 512 + k];
  hid[t] = fmaxf(a, 0.f);
  __syncthreads();
  if (t < 3) {
    float o = pb2[t];
    for (int k = 0; k < 256; k++) o += hid[k] * pW2[(size_t)t * 256 + k];
    out[(size_t)b * 3 + t] = o;
  }
}

// ---------------- launch ----------------
extern "C" void kernel_launch(void* const* d_in, const int* in_sizes, int n_in,
                              void* d_out, int out_size, void* d_ws, size_t ws_size,
                              hipStream_t stream)
{
  const float* emb    = (const float*)d_in[0];
  const float* cwih_f = (const float*)d_in[1];
  const float* cwhh_f = (const float*)d_in[2];
  const float* cb_f   = (const float*)d_in[3];
  const float* cwih_b = (const float*)d_in[4];
  const float* cwhh_b = (const float*)d_in[5];
  const float* cb_b   = (const float*)d_in[6];
  const float* awih_f = (const float*)d_in[7];
  const float* awhh_f = (const float*)d_in[8];
  const float* ab_f   = (const float*)d_in[9];
  const float* awih_b = (const float*)d_in[10];
  const float* awhh_b = (const float*)d_in[11];
  const float* ab_b   = (const float*)d_in[12];
  const float* pW1    = (const float*)d_in[13];
  const float* pb1    = (const float*)d_in[14];
  const float* pW2    = (const float*)d_in[15];
  const float* pb2    = (const float*)d_in[16];
  const int*   pidx   = (const int*)d_in[17];
  const int*   hidx   = (const int*)d_in[18];
  const float* w1 = (const float*)d_in[19];
  const float* w2 = (const float*)d_in[20];
  const float* w3 = (const float*)d_in[21];
  const float* w4 = (const float*)d_in[22];
  const float* w5 = (const float*)d_in[23];
  const float* w6 = (const float*)d_in[24];
  const float* w7 = (const float*)d_in[25];
  const float* w8 = (const float*)d_in[26];

  float* ws = (float*)d_ws;
  float* XG   = ws;
  float* X1   = ws + 16777216;
  float* X2   = X1 + 2457600;
  float* ALPH = X1;
  float* AG1  = ws + 16777216 + 2097152;
  float* AG2  = AG1 + (size_t)B_ * S_ * 160;
  float* CC   = ws + 21692416;

  k_embed<<<dim3(B_ * S_, 2), 256, 0, stream>>>(emb, pidx, hidx, X1, X2);
  gemm_abt<D_><<<dim3(64, 4, 4), 512, 0, stream>>>(X1, X2, cwih_f, cwih_b, cb_f, cb_b,
                                                   XG, B_ * S_, G4);
  k_lstm<<<dim3(B_, 4), 512, 0, stream>>>(XG, cwhh_f, cwhh_b, CC);
  k_full<<<dim3(B_, 4), 256, 0, stream>>>(CC, w1, w2, AG1, AG2);
  k_maxpool<<<dim3(B_, 2, 2), 512, 0, stream>>>(CC, w3, w4, AG1, AG2);
  k_alpha<<<dim3(B_, 2), 256, 0, stream>>>(CC, ALPH);
  k_att<<<dim3(B_, 4), 256, 0, stream>>>(CC, ALPH, w5, w6, w7, w8, AG1, AG2);
  gemm_abt<8 * L_><<<dim3(64, 4, 4), 512, 0, stream>>>(AG1, AG2, awih_f, awih_b, ab_f, ab_b,
                                                       XG, B_ * S_, G4);
  k_lstm<<<dim3(B_, 4), 512, 0, stream>>>(XG, awhh_f, awhh_b, CC);
  k_final<<<dim3(B_), 256, 0, stream>>>(CC, pW1, pb1, pW2, pb2, (float*)d_out);
}

// Round 14
// 612.885 us; speedup vs baseline: 1.0484x; 1.0484x over previous
//
#include <hip/hip_runtime.h>
#include <math.h>

// ---------------- problem constants ----------------
#define B_  64
#define S_  128
#define H_  128
#define D_  300
#define L_  20
#define G4  512                 // 4*H
#define SH  (S_*H_)             // 16384
#define BSH ((size_t)B_*SH)     // 1048576
#define EPSV 1e-8f

typedef __attribute__((ext_vector_type(8))) short bshort8;   // 8 bf16 (4 VGPR)
typedef __attribute__((ext_vector_type(4))) float f32x4;     // MFMA C/D

// monotonic float<->uint mapping for atomicMax on floats (handles negatives)
__device__ __forceinline__ unsigned fmap(float f){
  unsigned u = __float_as_uint(f);
  return (u & 0x80000000u) ? ~u : (u | 0x80000000u);
}
__device__ __forceinline__ float funmap(unsigned u){
  return __uint_as_float((u & 0x80000000u) ? (u & 0x7fffffffu) : ~u);
}
// NaN-safe fast activations (__expf; gates here are O(1), err ~1e-6).
// Verified numerically safe: R11/R12/R13 passes with unchanged absmax.
__device__ __forceinline__ float fsigm(float x){ return 1.f/(1.f+__expf(-x)); }
__device__ __forceinline__ float ftanh(float x){ return 1.f - 2.f/(__expf(2.f*x)+1.f); }
__device__ __forceinline__ float dot4(float4 a, float4 b){
  return a.x*b.x + a.y*b.y + a.z*b.z + a.w*b.w;
}
// wave-uniform broadcast of lane k's value (SGPR), no LDS pipe
__device__ __forceinline__ float blane(float v, int k){
  return __int_as_float(__builtin_amdgcn_readlane(__float_as_int(v), k));
}
// fp32 -> bf16 round-to-nearest-even
__device__ __forceinline__ unsigned short f2bf(float f){
  unsigned u = __float_as_uint(f);
  unsigned r = u + 0x7fffu + ((u >> 16) & 1u);
  return (unsigned short)(r >> 16);
}
__device__ __forceinline__ float bf2f(unsigned short us){
  return __uint_as_float(((unsigned)us) << 16);
}
// XOR swizzles: row-major [row][cols], float4-index XOR'd with (row>>3)
__device__ __forceinline__ int swz64(int row, int h){   // 64 cols
  return (row << 6) + ((((h >> 2) ^ ((row >> 3) & 15)) << 2) | (h & 3));
}
__device__ __forceinline__ int swz128(int row, int h){  // 128 cols
  return (row << 7) + ((((h >> 2) ^ ((row >> 3) & 15)) << 2) | (h & 3));
}
// bf16 LDS swizzle: row-major [128 rows][128 h] halfwords; 16B slot XOR row&15
__device__ __forceinline__ int bswz(int row, int slot){  // slot = h>>3
  return (row << 7) + (((slot ^ (row & 15)) << 3));
}
// split fp32 -> (hi,lo) bf16 packs: 8 floats -> 2x int4 (8 bf16 each)
__device__ __forceinline__ void cvt8(float4 a0, float4 a1, int4& hi, int4& lo){
  float v[8] = {a0.x, a0.y, a0.z, a0.w, a1.x, a1.y, a1.z, a1.w};
  unsigned short h[8], l[8];
  #pragma unroll
  for (int i = 0; i < 8; i++) {
    h[i] = f2bf(v[i]);
    float d = v[i] - bf2f(h[i]);
    l[i] = f2bf(d);
  }
  hi = make_int4((unsigned)h[0] | ((unsigned)h[1] << 16), (unsigned)h[2] | ((unsigned)h[3] << 16),
                 (unsigned)h[4] | ((unsigned)h[5] << 16), (unsigned)h[6] | ((unsigned)h[7] << 16));
  lo = make_int4((unsigned)l[0] | ((unsigned)l[1] << 16), (unsigned)l[2] | ((unsigned)l[3] << 16),
                 (unsigned)l[4] | ((unsigned)l[5] << 16), (unsigned)l[6] | ((unsigned)l[7] << 16));
}

// ---------------- embedding gather ----------------
__global__ void k_embed(const float* __restrict__ emb, const int* __restrict__ p,
                        const int* __restrict__ h, float* __restrict__ x1,
                        float* __restrict__ x2)
{
  int row = blockIdx.x;
  const int* idx = blockIdx.y ? h : p;
  float* x = blockIdx.y ? x2 : x1;
  int tok = idx[row];
  const float* src = emb + (size_t)tok * D_;
  float* dst = x + (size_t)row * D_;
  for (int d = threadIdx.x; d < D_; d += blockDim.x) dst[d] = src[d];
}

// ---------------- GEMM (split-bf16 MFMA): C = A(M,K) * W(N,K)^T + bias ----
// fp32 emulated as hi+lo bf16; C = Ah*Wh + Ah*Wl + Al*Wh (lo*lo dropped,
// rel err ~2^-17). 128x128 tile, 8 waves as 4(M)x2(N) grid of 16x16 MFMA
// tiles per wave, BK=32.
template<int K>
__global__ __launch_bounds__(512, 1) void gemm_abt(
    const float* __restrict__ A0, const float* __restrict__ A1,
    const float* __restrict__ W0, const float* __restrict__ W1,
    const float* __restrict__ b0, const float* __restrict__ b1,
    float* __restrict__ Cbase, int M, int N)
{
  int q = blockIdx.z;
  const float* A = (q >> 1) ? A1 : A0;
  const float* W = (q & 1) ? W1 : W0;
  const float* bias = (q & 1) ? b1 : b0;
  float* Cm = Cbase + (size_t)q * M * N;

  __shared__ __align__(16) short AsH[128 * 32];
  __shared__ __align__(16) short AsL[128 * 32];
  __shared__ __align__(16) short WsH[128 * 32];
  __shared__ __align__(16) short WsL[128 * 32];

  int t = threadIdx.x;
  int w = t >> 6, lane = t & 63;
  int r = lane & 15, g = lane >> 4;
  int m0 = blockIdx.x * 128, n0 = blockIdx.y * 128;
  int mbase = (w & 1) * 64;        // 4 m-tiles of 16
  int nbase = (w >> 1) * 32;       // 2 n-tiles of 16

  f32x4 acc[4][2];
  #pragma unroll
  for (int i = 0; i < 4; i++)
    #pragma unroll
    for (int j = 0; j < 2; j++) acc[i][j] = (f32x4){0.f, 0.f, 0.f, 0.f};

  int srow = t >> 2, skc = t & 3;                     // staging: row, k-chunk
  int soff = srow * 32 + ((skc ^ ((srow >> 1) & 3)) << 3);

  #pragma unroll 1
  for (int k0 = 0; k0 < K; k0 += 32) {
    {
      int gk = k0 + (skc << 3);
      float4 z = make_float4(0.f, 0.f, 0.f, 0.f);
      float4 a0v = z, a1v = z, w0v = z, w1v = z;
      if (gk < K) {
        a0v = *(const float4*)&A[(size_t)(m0 + srow) * K + gk];
        w0v = *(const float4*)&W[(size_t)(n0 + srow) * K + gk];
      }
      if (gk + 4 < K) {
        a1v = *(const float4*)&A[(size_t)(m0 + srow) * K + gk + 4];
        w1v = *(const float4*)&W[(size_t)(n0 + srow) * K + gk + 4];
      }
      int4 hi, lo;
      cvt8(a0v, a1v, hi, lo);
      *(int4*)&AsH[soff] = hi; *(int4*)&AsL[soff] = lo;
      cvt8(w0v, w1v, hi, lo);
      *(int4*)&WsH[soff] = hi; *(int4*)&WsL[soff] = lo;
    }
    __syncthreads();
    bshort8 ah[4], al[4], bh[2], bl[2];
    #pragma unroll
    for (int i = 0; i < 4; i++) {
      int R = mbase + i * 16 + r;
      int off = R * 32 + ((g ^ ((R >> 1) & 3)) << 3);
      ah[i] = *(const bshort8*)&AsH[off];
      al[i] = *(const bshort8*)&AsL[off];
    }
    #pragma unroll
    for (int j = 0; j < 2; j++) {
      int R = nbase + j * 16 + r;
      int off = R * 32 + ((g ^ ((R >> 1) & 3)) << 3);
      bh[j] = *(const bshort8*)&WsH[off];
      bl[j] = *(const bshort8*)&WsL[off];
    }
    #pragma unroll
    for (int i = 0; i < 4; i++)
      #pragma unroll
      for (int j = 0; j < 2; j++) {
        acc[i][j] = __builtin_amdgcn_mfma_f32_16x16x32_bf16(ah[i], bh[j], acc[i][j], 0, 0, 0);
        acc[i][j] = __builtin_amdgcn_mfma_f32_16x16x32_bf16(ah[i], bl[j], acc[i][j], 0, 0, 0);
        acc[i][j] = __builtin_amdgcn_mfma_f32_16x16x32_bf16(al[i], bh[j], acc[i][j], 0, 0, 0);
      }
    __syncthreads();
  }
  // epilogue: C/D layout col=lane&15, row=(lane>>4)*4+reg (HW-verified)
  #pragma unroll
  for (int j = 0; j < 2; j++) {
    int gcol = n0 + nbase + j * 16 + r;
    float bv = bias[gcol];
    #pragma unroll
    for (int i = 0; i < 4; i++) {
      #pragma unroll
      for (int rg = 0; rg < 4; rg++) {
        int grow = m0 + mbase + i * 16 + g * 4 + rg;
        Cm[(size_t)grow * N + gcol] = acc[i][j][rg] + bv;
      }
    }
  }
}

// ---------------- LSTM scan ----------------
// R14 = R12's proven base (2 barriers, 2-wave activation, fast acts) with
// ONLY the dot swapped for R13's verified gate-pair version: thread t owns
// gates (j, j+256) over k-half kh -> 64 readlane + 128 FMA per step (each
// broadcast feeds two FMAs), vs 128+128 before. Issue 2048->1536 wave-instr.
__global__ __launch_bounds__(512, 1) void k_lstm(const float* __restrict__ xg,
    const float* __restrict__ whhF, const float* __restrict__ whhB,
    float* __restrict__ hs)
{
  int b = blockIdx.x, q = blockIdx.y, dir = q & 1;
  const float* whh = dir ? whhB : whhF;
  const float* xgq = xg + ((size_t)(q * B_ + b)) * (S_ * G4);
  float* out = hs + ((size_t)(q * B_ + b)) * SH;
  int t = threadIdx.x;
  int j = t & 255;                 // gate pair (j, j+256)
  int kh = t >> 8;                 // k-half (wave-uniform: waves 0-3 / 4-7)
  int lane = t & 63;

  float2 w2[64];                   // w2[k] = (whh[j][kh*64+k], whh[j+256][kh*64+k])
  {
    const float* wr0 = whh + (size_t)j * 128 + kh * 64;
    const float* wr1 = whh + (size_t)(j + 256) * 128 + kh * 64;
    #pragma unroll
    for (int k = 0; k < 64; k += 4) {
      float4 v0 = *(const float4*)(wr0 + k);
      float4 v1 = *(const float4*)(wr1 + k);
      w2[k]     = make_float2(v0.x, v1.x);
      w2[k + 1] = make_float2(v0.y, v1.y);
      w2[k + 2] = make_float2(v0.z, v1.z);
      w2[k + 3] = make_float2(v0.w, v1.w);
    }
  }
  __shared__ float hsm[128];
  __shared__ float csm[128];
  __shared__ float gsm[2][512];    // [khalf][gate]
  if (t < 128) { hsm[t] = 0.f; csm[t] = 0.f; }
  __syncthreads();

  float hreg = 0.f;                // wave-replicated h[kh*64 + lane]
  float xn0 = 0.f, xn1 = 0.f;
  if (kh == 0) {
    int t0 = dir ? (S_ - 1) : 0;
    xn0 = xgq[(size_t)t0 * G4 + j];
    xn1 = xgq[(size_t)t0 * G4 + j + 256];
  }

  for (int st = 0; st < S_; st++) {
    int tt = dir ? (S_ - 1 - st) : st;
    float x0 = xn0, x1 = xn1;
    if (kh == 0) {                  // wave-uniform branch: prefetch next step
      int stn = (st + 1 < S_) ? st + 1 : st;
      int ttn = dir ? (S_ - 1 - stn) : stn;
      xn0 = xgq[(size_t)ttn * G4 + j];
      xn1 = xgq[(size_t)ttn * G4 + j + 256];
    }
    // dot: 4 chains x 2 gates; each blane feeds two FMAs
    float a0x = (kh == 0) ? x0 : 0.f, a0y = (kh == 0) ? x1 : 0.f;
    float a1x = 0.f, a1y = 0.f, a2x = 0.f, a2y = 0.f, a3x = 0.f, a3y = 0.f;
    #pragma unroll
    for (int k = 0; k < 64; k += 4) {
      float s0 = blane(hreg, k);
      float s1 = blane(hreg, k + 1);
      float s2 = blane(hreg, k + 2);
      float s3 = blane(hreg, k + 3);
      a0x += w2[k].x * s0;     a0y += w2[k].y * s0;
      a1x += w2[k + 1].x * s1; a1y += w2[k + 1].y * s1;
      a2x += w2[k + 2].x * s2; a2y += w2[k + 2].y * s2;
      a3x += w2[k + 3].x * s3; a3y += w2[k + 3].y * s3;
    }
    gsm[kh][j]       = (a0x + a1x) + (a2x + a3x);
    gsm[kh][j + 256] = (a0y + a1y) + (a2y + a3y);
    __syncthreads();
    if (t < 128) {                  // R12-style 2-wave activation, c/h in LDS
      float gi = gsm[0][t]       + gsm[1][t];
      float gf = gsm[0][128 + t] + gsm[1][128 + t];
      float gg = gsm[0][256 + t] + gsm[1][256 + t];
      float go = gsm[0][384 + t] + gsm[1][384 + t];
      float ig = fsigm(gi);
      float fg = fsigm(gf);
      float gv = ftanh(gg);
      float og = fsigm(go);
      float c = fg * csm[t] + ig * gv;
      float hn = og * ftanh(c);
      csm[t] = c; hsm[t] = hn;
      out[(size_t)tt * H_ + t] = hn;
    }
    __syncthreads();
    hreg = hsm[kh * 64 + lane];
  }
}

// ---------------- full matching ----------------
__global__ __launch_bounds__(256) void k_full(const float* __restrict__ C,
    const float* __restrict__ w1, const float* __restrict__ w2,
    float* __restrict__ ag1, float* __restrict__ ag2)
{
  int b = blockIdx.x, q = blockIdx.y, dir = q & 1;
  const float* p1  = C + (size_t)q * BSH + (size_t)b * SH;
  const float* p2l = C + (size_t)((q + 2) & 3) * BSH + (size_t)b * SH + (size_t)(S_ - 1) * H_;
  const float* w = dir ? w2 : w1;
  float* out = (q < 2 ? ag1 : ag2) + (size_t)b * S_ * 160;

  __shared__ float p1s[SH];
  __shared__ float ws2[H_][L_];
  __shared__ float p2s[H_];
  __shared__ float n2s[L_];
  int t = threadIdx.x;
  for (int i = t; i < SH; i += 256) p1s[i] = p1[i];
  for (int i = t; i < H_ * L_; i += 256) { float v = w[i]; ws2[i / L_][i % L_] = v * v; }
  if (t < H_) p2s[t] = p2l[t];
  __syncthreads();
  if (t < L_) {
    float s = 0.f;
    for (int hh = 0; hh < H_; hh++) { float v = p2s[hh]; s += v * v * ws2[hh][t]; }
    n2s[t] = sqrtf(s);
  }
  __syncthreads();
  for (int i = t; i < S_ * L_; i += 256) {
    int s = i / L_, l = i % L_;
    const float* pr = p1s + s * H_;
    float dot = 0.f, n1 = 0.f;
    for (int hh = 0; hh < H_; hh++) {
      float a = pr[hh], ww = ws2[hh][l];
      dot += a * p2s[hh] * ww;
      n1 += a * a * ww;
    }
    n1 = sqrtf(n1);
    out[(size_t)s * 160 + dir * L_ + l] = dot / (fmaxf(n1, EPSV) * fmaxf(n2s[l], EPSV));
  }
}

// ---------------- maxpool matching (bf16 MFMA) ----------------
__global__ __launch_bounds__(512, 1) void k_maxpool(const float* __restrict__ C,
    const float* __restrict__ w3, const float* __restrict__ w4,
    float* __restrict__ ag1, float* __restrict__ ag2)
{
  int b = blockIdx.x, dir = blockIdx.y, lh = blockIdx.z;
  const float* p1 = C + (size_t)(0 + dir) * BSH + (size_t)b * SH;
  const float* p2 = C + (size_t)(2 + dir) * BSH + (size_t)b * SH;
  const float* w = dir ? w4 : w3;

  __shared__ __align__(16) short P1b[128 * 128];
  __shared__ __align__(16) short P2b[128 * 128];
  __shared__ __align__(16) short Ab[128 * 128];
  __shared__ float w2s[128 * 10];
  __shared__ float n1s[128], n2s[128];
  __shared__ unsigned mx2u[128];

  int t = threadIdx.x;
  int wv = t >> 6, lane = t & 63;
  int g = lane >> 4, col = lane & 15;

  for (int i = t; i < 8192; i += 512) {
    int row = i >> 6, hp = i & 63;
    int phys = bswz(row, hp >> 2) + ((hp & 3) << 1);
    float2 v1 = *(const float2*)&p1[(row << 7) + (hp << 1)];
    float2 v2 = *(const float2*)&p2[(row << 7) + (hp << 1)];
    *(unsigned*)&P1b[phys] = (unsigned)f2bf(v1.x) | ((unsigned)f2bf(v1.y) << 16);
    *(unsigned*)&P2b[phys] = (unsigned)f2bf(v2.x) | ((unsigned)f2bf(v2.y) << 16);
  }
  for (int i = t; i < 128 * 10; i += 512) {
    int hh = i / 10, lq = i % 10;
    float wv_ = w[hh * L_ + lh * 10 + lq];
    w2s[i] = wv_ * wv_;
  }
  __syncthreads();

  #pragma unroll 1
  for (int lq = 0; lq < 10; lq++) {
    int lout = lh * 10 + lq;
    for (int i = t; i < 8192; i += 512) {
      int row = i >> 6, hp = i & 63;
      int phys = bswz(row, hp >> 2) + ((hp & 3) << 1);
      unsigned u = *(const unsigned*)&P1b[phys];
      float lo = bf2f((unsigned short)(u & 0xffffu)) * w2s[(hp << 1) * 10 + lq];
      float hi = bf2f((unsigned short)(u >> 16))     * w2s[((hp << 1) + 1) * 10 + lq];
      *(unsigned*)&Ab[phys] = (unsigned)f2bf(lo) | ((unsigned)f2bf(hi) << 16);
    }
    {
      int s = t >> 2, part = t & 3;
      float s1 = 0.f, s2 = 0.f;
      #pragma unroll 1
      for (int hp = part * 16; hp < part * 16 + 16; hp++) {
        int phys = bswz(s, hp >> 2) + ((hp & 3) << 1);
        unsigned u1 = *(const unsigned*)&P1b[phys];
        unsigned u2 = *(const unsigned*)&P2b[phys];
        float wlo = w2s[(hp << 1) * 10 + lq];
        float whi = w2s[((hp << 1) + 1) * 10 + lq];
        float a = bf2f((unsigned short)(u1 & 0xffffu)), bb = bf2f((unsigned short)(u1 >> 16));
        float c2 = bf2f((unsigned short)(u2 & 0xffffu)), d2 = bf2f((unsigned short)(u2 >> 16));
        s1 += a * a * wlo + bb * bb * whi;
        s2 += c2 * c2 * wlo + d2 * d2 * whi;
      }
      s1 += __shfl_xor(s1, 1, 64); s1 += __shfl_xor(s1, 2, 64);
      s2 += __shfl_xor(s2, 1, 64); s2 += __shfl_xor(s2, 2, 64);
      if (part == 0) { n1s[s] = sqrtf(s1); n2s[s] = sqrtf(s2); }
    }
    if (t < 128) mx2u[t] = fmap(-3.4e38f);
    __syncthreads();

    {
      int mrow = (wv << 4) + col;
      f32x4 acc0 = {0,0,0,0}, acc1 = {0,0,0,0}, acc2 = {0,0,0,0}, acc3 = {0,0,0,0};
      f32x4 acc4 = {0,0,0,0}, acc5 = {0,0,0,0}, acc6 = {0,0,0,0}, acc7 = {0,0,0,0};
      #pragma unroll 1
      for (int k0 = 0; k0 < 128; k0 += 32) {
        int slot = ((k0 >> 3) + g) ^ col;
        bshort8 av = *(const bshort8*)&Ab[(mrow << 7) + (slot << 3)];
        bshort8 bv0 = *(const bshort8*)&P2b[((0 << 4) + col << 7) + (slot << 3)];
        bshort8 bv1 = *(const bshort8*)&P2b[(((1 << 4) + col) << 7) + (slot << 3)];
        bshort8 bv2 = *(const bshort8*)&P2b[(((2 << 4) + col) << 7) + (slot << 3)];
        bshort8 bv3 = *(const bshort8*)&P2b[(((3 << 4) + col) << 7) + (slot << 3)];
        bshort8 bv4 = *(const bshort8*)&P2b[(((4 << 4) + col) << 7) + (slot << 3)];
        bshort8 bv5 = *(const bshort8*)&P2b[(((5 << 4) + col) << 7) + (slot << 3)];
        bshort8 bv6 = *(const bshort8*)&P2b[(((6 << 4) + col) << 7) + (slot << 3)];
        bshort8 bv7 = *(const bshort8*)&P2b[(((7 << 4) + col) << 7) + (slot << 3)];
        acc0 = __builtin_amdgcn_mfma_f32_16x16x32_bf16(av, bv0, acc0, 0, 0, 0);
        acc1 = __builtin_amdgcn_mfma_f32_16x16x32_bf16(av, bv1, acc1, 0, 0, 0);
        acc2 = __builtin_amdgcn_mfma_f32_16x16x32_bf16(av, bv2, acc2, 0, 0, 0);
        acc3 = __builtin_amdgcn_mfma_f32_16x16x32_bf16(av, bv3, acc3, 0, 0, 0);
        acc4 = __builtin_amdgcn_mfma_f32_16x16x32_bf16(av, bv4, acc4, 0, 0, 0);
        acc5 = __builtin_amdgcn_mfma_f32_16x16x32_bf16(av, bv5, acc5, 0, 0, 0);
        acc6 = __builtin_amdgcn_mfma_f32_16x16x32_bf16(av, bv6, acc6, 0, 0, 0);
        acc7 = __builtin_amdgcn_mfma_f32_16x16x32_bf16(av, bv7, acc7, 0, 0, 0);
      }
      float n1v[4];
      #pragma unroll
      for (int r = 0; r < 4; r++) n1v[r] = n1s[(wv << 4) + (g << 2) + r];
      float rm[4] = {-3.4e38f, -3.4e38f, -3.4e38f, -3.4e38f};
      float cm[8];
      f32x4 accs[8] = {acc0, acc1, acc2, acc3, acc4, acc5, acc6, acc7};
      #pragma unroll
      for (int c = 0; c < 8; c++) {
        float n2v = n2s[(c << 4) + col];
        float cmx = -3.4e38f;
        #pragma unroll
        for (int r = 0; r < 4; r++) {
          float deno = n1v[r] * n2v;
          float cs = accs[c][r] / (deno > EPSV ? deno : EPSV);
          rm[r] = fmaxf(rm[r], cs);
          cmx = fmaxf(cmx, cs);
        }
        cm[c] = cmx;
      }
      #pragma unroll
      for (int m = 1; m < 16; m <<= 1)
        #pragma unroll
        for (int r = 0; r < 4; r++) rm[r] = fmaxf(rm[r], __shfl_xor(rm[r], m, 64));
      if (col == 0) {
        #pragma unroll
        for (int r = 0; r < 4; r++) {
          int srow = (wv << 4) + (g << 2) + r;
          ag1[(size_t)b * S_ * 160 + (size_t)srow * 160 + 40 + dir * L_ + lout] = rm[r];
        }
      }
      #pragma unroll
      for (int c = 0; c < 8; c++) {
        cm[c] = fmaxf(cm[c], __shfl_xor(cm[c], 16, 64));
        cm[c] = fmaxf(cm[c], __shfl_xor(cm[c], 32, 64));
      }
      if (lane < 16) {
        #pragma unroll
        for (int c = 0; c < 8; c++) atomicMax(&mx2u[(c << 4) + lane], fmap(cm[c]));
      }
    }
    __syncthreads();
    if (t < 128)
      ag2[(size_t)b * S_ * 160 + (size_t)t * 160 + 40 + dir * L_ + lout] = funmap(mx2u[t]);
    __syncthreads();
  }
}

// ---------------- alpha (plain cosine matrix) ----------------
__global__ __launch_bounds__(256, 1) void k_alpha(const float* __restrict__ C,
                                                  float* __restrict__ alpha)
{
  int b = blockIdx.x, dir = blockIdx.y;
  const float* p1 = C + (size_t)(0 + dir) * BSH + (size_t)b * SH;
  const float* p2 = C + (size_t)(2 + dir) * BSH + (size_t)b * SH;
  __shared__ __align__(16) float a1[128 * 64];
  __shared__ __align__(16) float a2[128 * 64];
  __shared__ float n1p[128], n2p[128];
  int t = threadIdx.x, tx = t & 15, ty = t >> 4;
  float acc[8][8] = {};

  for (int pass = 0; pass < 2; pass++) {
    int h0 = pass << 6;
    for (int i = t; i < 128 * 64; i += 256) {
      int row = i >> 6, hh = i & 63;
      int off = swz64(row, hh);
      a1[off] = p1[(size_t)row * H_ + h0 + hh];
      a2[off] = p2[(size_t)row * H_ + h0 + hh];
    }
    __syncthreads();
    {
      int r = t & 127;
      const float* a = (t < 128) ? a1 : a2;
      float s = 0.f;
      #pragma unroll 1
      for (int f = 0; f < 16; f++) {
        float4 v = *(const float4*)&a[(r << 6) + ((f ^ ((r >> 3) & 15)) << 2)];
        s += dot4(v, v);
      }
      float* np = (t < 128) ? n1p : n2p;
      if (pass == 0) np[r] = s; else np[r] += s;
    }
    #pragma unroll 1
    for (int f = 0; f < 16; f++) {
      int cx = ((f ^ ty) << 2);
      int cy = ((f ^ tx) << 2);
      float4 x[8], y[8];
      #pragma unroll
      for (int i = 0; i < 8; i++) x[i] = *(const float4*)&a1[((8 * ty + i) << 6) + cx];
      #pragma unroll
      for (int j = 0; j < 8; j++) y[j] = *(const float4*)&a2[((8 * tx + j) << 6) + cy];
      #pragma unroll
      for (int i = 0; i < 8; i++)
        #pragma unroll
        for (int j = 0; j < 8; j++) acc[i][j] += dot4(x[i], y[j]);
    }
    __syncthreads();
  }
  float inv1[8], inv2[8];
  #pragma unroll
  for (int i = 0; i < 8; i++) inv1[i] = 1.f / fmaxf(sqrtf(n1p[8 * ty + i]), EPSV);
  #pragma unroll
  for (int j = 0; j < 8; j++) inv2[j] = 1.f / fmaxf(sqrtf(n2p[8 * tx + j]), EPSV);
  float* outp = alpha + ((size_t)dir * B_ + b) * SH;
  #pragma unroll
  for (int i = 0; i < 8; i++) {
    int ss = 8 * ty + i;
    float s1 = inv1[i];
    float4 o0 = make_float4(acc[i][0] * s1 * inv2[0], acc[i][1] * s1 * inv2[1],
                            acc[i][2] * s1 * inv2[2], acc[i][3] * s1 * inv2[3]);
    float4 o1 = make_float4(acc[i][4] * s1 * inv2[4], acc[i][5] * s1 * inv2[5],
                            acc[i][6] * s1 * inv2[6], acc[i][7] * s1 * inv2[7]);
    *(float4*)&outp[(size_t)ss * S_ + 8 * tx] = o0;
    *(float4*)&outp[(size_t)ss * S_ + 8 * tx + 4] = o1;
  }
}

// ---------------- attentive matching ----------------
__global__ __launch_bounds__(256, 1) void k_att(const float* __restrict__ C,
    const float* __restrict__ alpha,
    const float* __restrict__ w5, const float* __restrict__ w6,
    const float* __restrict__ w7, const float* __restrict__ w8,
    float* __restrict__ ag1, float* __restrict__ ag2)
{
  int b = blockIdx.x, q = blockIdx.y, dir = q & 1;
  const float* p1  = C + (size_t)q * BSH + (size_t)b * SH;
  const float* m2g = C + (size_t)((q + 2) & 3) * BSH + (size_t)b * SH;
  const float* wa = dir ? w6 : w5;
  const float* wm = dir ? w8 : w7;
  const float* ain = alpha + ((size_t)dir * B_ + b) * SH;
  float* out = (q < 2 ? ag1 : ag2) + (size_t)b * S_ * 160;
  bool tr = (q >= 2);

  __shared__ __align__(16) float A[128 * 128];
  __shared__ __align__(16) float M2T[128 * 128];
  __shared__ __align__(16) float waT[20 * 128];
  __shared__ __align__(16) float wmT[20 * 128];
  __shared__ float rowsum[128];
  __shared__ int   midx[128];
  int t = threadIdx.x, tx = t & 15, ty = t >> 4;

  for (int i = t; i < SH; i += 256) {
    int r = i >> 7, c = i & 127;
    float av = ain[i];
    if (tr) A[swz128(c, r)] = av; else A[swz128(r, c)] = av;
    M2T[swz128(c, r)] = m2g[i];
  }
  for (int i = t; i < H_ * L_; i += 256) {
    int hh = i / L_, l = i % L_;
    float v = wa[i]; waT[l * 128 + hh] = v * v;
    float u = wm[i]; wmT[l * 128 + hh] = u * u;
  }
  __syncthreads();

  if (t < 128) {
    float sum = 0.f, best = -3.4e38f; int bi = 0;
    #pragma unroll 1
    for (int f = 0; f < 32; f++) {
      float4 v = *(const float4*)&A[(t << 7) + (((f ^ ((t >> 3) & 15)) & 31) << 2)];
      sum += v.x + v.y + v.z + v.w;
      int k = f << 2;
      if (v.x > best) { best = v.x; bi = k; }
      if (v.y > best) { best = v.y; bi = k + 1; }
      if (v.z > best) { best = v.z; bi = k + 2; }
      if (v.w > best) { best = v.w; bi = k + 3; }
    }
    rowsum[t] = sum; midx[t] = bi;
  }
  __syncthreads();

  float acc[8][8] = {};
  #pragma unroll 1
  for (int f = 0; f < 32; f++) {
    int cx = (((f ^ ty) & 31) << 2);
    int cy = (((f ^ tx) & 31) << 2);
    float4 x[8], y[8];
    #pragma unroll
    for (int i = 0; i < 8; i++) x[i] = *(const float4*)&A[((8 * ty + i) << 7) + cx];
    #pragma unroll
    for (int j = 0; j < 8; j++) y[j] = *(const float4*)&M2T[((8 * tx + j) << 7) + cy];
    #pragma unroll
    for (int i = 0; i < 8; i++)
      #pragma unroll
      for (int j = 0; j < 8; j++) acc[i][j] += dot4(x[i], y[j]);
  }
  __syncthreads();
  {
    float rinv[8];
    #pragma unroll
    for (int i = 0; i < 8; i++) rinv[i] = 1.f / rowsum[8 * ty + i];
    #pragma unroll
    for (int i = 0; i < 8; i++) {
      int row = 8 * ty + i;
      int f0 = (2 * tx) ^ ((row >> 3) & 15);
      int f1 = (2 * tx + 1) ^ ((row >> 3) & 15);
      float4 o0 = make_float4(acc[i][0] * rinv[i], acc[i][1] * rinv[i],
                              acc[i][2] * rinv[i], acc[i][3] * rinv[i]);
      float4 o1 = make_float4(acc[i][4] * rinv[i], acc[i][5] * rinv[i],
                              acc[i][6] * rinv[i], acc[i][7] * rinv[i]);
      *(float4*)&A[(row << 7) + (f0 << 2)] = o0;
      *(float4*)&A[(row << 7) + (f1 << 2)] = o1;
    }
  }
  __syncthreads();

  {
    int s = t >> 1, l0 = (t & 1) * 10;
    int mi = midx[s];
    const float* m2r = m2g + (size_t)mi * H_;
    const float* p1r = p1 + (size_t)s * H_;
    float dA[10] = {}, nA[10] = {}, bA[10] = {};
    float dM[10] = {}, nM[10] = {}, bM[10] = {};
    #pragma unroll 1
    for (int f = 0; f < 32; f++) {
      float4 pv = *(const float4*)&p1r[f << 2];
      float4 mv = *(const float4*)&m2r[f << 2];
      float4 av = *(const float4*)&A[(s << 7) + (((f ^ ((s >> 3) & 15)) & 31) << 2)];
      float4 ap = make_float4(av.x*pv.x, av.y*pv.y, av.z*pv.z, av.w*pv.w);
      float4 a2 = make_float4(av.x*av.x, av.y*av.y, av.z*av.z, av.w*av.w);
      float4 p2 = make_float4(pv.x*pv.x, pv.y*pv.y, pv.z*pv.z, pv.w*pv.w);
      float4 mp = make_float4(mv.x*pv.x, mv.y*pv.y, mv.z*pv.z, mv.w*pv.w);
      float4 m2 = make_float4(mv.x*mv.x, mv.y*mv.y, mv.z*mv.z, mv.w*mv.w);
      #pragma unroll
      for (int l = 0; l < 10; l++) {
        float4 wv = *(const float4*)&waT[(l0 + l) * 128 + (f << 2)];
        dA[l] += dot4(ap, wv); nA[l] += dot4(a2, wv); bA[l] += dot4(p2, wv);
        float4 uv = *(const float4*)&wmT[(l0 + l) * 128 + (f << 2)];
        dM[l] += dot4(mp, uv); nM[l] += dot4(m2, uv); bM[l] += dot4(p2, uv);
      }
    }
    #pragma unroll
    for (int l = 0; l < 10; l++) {
      int ll = l0 + l;
      out[(size_t)s * 160 + 80  + dir * L_ + ll] =
          dA[l] / (fmaxf(sqrtf(nA[l]), EPSV) * fmaxf(sqrtf(bA[l]), EPSV));
      out[(size_t)s * 160 + 120 + dir * L_ + ll] =
          dM[l] / (fmaxf(sqrtf(nM[l]), EPSV) * fmaxf(sqrtf(bM[l]), EPSV));
    }
  }
}

// ---------------- final MLP ----------------
__global__ __launch_bounds__(256) void k_final(const float* __restrict__ Cc,
    const float* __restrict__ pW1, const float* __restrict__ pb1,
    const float* __restrict__ pW2, const float* __restrict__ pb2,
    float* __restrict__ out)
{
  int b = blockIdx.x, t = threadIdx.x;
  __shared__ float cat[512];
  __shared__ float hid[256];
  if (t < 128) {
    cat[t]       = Cc[(size_t)(0 * B_ + b) * SH + (size_t)(S_ - 1) * H_ + t];
    cat[128 + t] = Cc[(size_t)(1 * B_ + b) * SH + (size_t)(S_ - 1) * H_ + t];
    cat[256 + t] = Cc[(size_t)(2 * B_ + b) * SH + (size_t)(S_ - 1) * H_ + t];
    cat[384 + t] = Cc[(size_t)(3 * B_ + b) * SH + (size_t)(S_ - 1) * H_ + t];
  }
  __syncthreads();
  float a = pb1[t];
  for (int k = 0; k < 512; k++) a += cat[k] * pW1[(size_t)t * 512 + k];
  hid[t] = fmaxf(a, 0.f);
  __syncthreads();
  if (t < 3) {
    float o = pb2[t];
    for (int k = 0; k < 256; k++) o += hid[k] * pW2[(size_t)t * 256 + k];
    out[(size_t)b * 3 + t] = o;
  }
}

// ---------------- launch ----------------
extern "C" void kernel_launch(void* const* d_in, const int* in_sizes, int n_in,
                              void* d_out, int out_size, void* d_ws, size_t ws_size,
                              hipStream_t stream)
{
  const float* emb    = (const float*)d_in[0];
  const float* cwih_f = (const float*)d_in[1];
  const float* cwhh_f = (const float*)d_in[2];
  const float* cb_f   = (const float*)d_in[3];
  const float* cwih_b = (const float*)d_in[4];
  const float* cwhh_b = (const float*)d_in[5];
  const float* cb_b   = (const float*)d_in[6];
  const float* awih_f = (const float*)d_in[7];
  const float* awhh_f = (const float*)d_in[8];
  const float* ab_f   = (const float*)d_in[9];
  const float* awih_b = (const float*)d_in[10];
  const float* awhh_b = (const float*)d_in[11];
  const float* ab_b   = (const float*)d_in[12];
  const float* pW1    = (const float*)d_in[13];
  const float* pb1    = (const float*)d_in[14];
  const float* pW2    = (const float*)d_in[15];
  const float* pb2    = (const float*)d_in[16];
  const int*   pidx   = (const int*)d_in[17];
  const int*   hidx   = (const int*)d_in[18];
  const float* w1 = (const float*)d_in[19];
  const float* w2 = (const float*)d_in[20];
  const float* w3 = (const float*)d_in[21];
  const float* w4 = (const float*)d_in[22];
  const float* w5 = (const float*)d_in[23];
  const float* w6 = (const float*)d_in[24];
  const float* w7 = (const float*)d_in[25];
  const float* w8 = (const float*)d_in[26];

  float* ws = (float*)d_ws;
  float* XG   = ws;
  float* X1   = ws + 16777216;
  float* X2   = X1 + 2457600;
  float* ALPH = X1;
  float* AG1  = ws + 16777216 + 2097152;
  float* AG2  = AG1 + (size_t)B_ * S_ * 160;
  float* CC   = ws + 21692416;

  k_embed<<<dim3(B_ * S_, 2), 256, 0, stream>>>(emb, pidx, hidx, X1, X2);
  gemm_abt<D_><<<dim3(64, 4, 4), 512, 0, stream>>>(X1, X2, cwih_f, cwih_b, cb_f, cb_b,
                                                   XG, B_ * S_, G4);
  k_lstm<<<dim3(B_, 4), 512, 0, stream>>>(XG, cwhh_f, cwhh_b, CC);
  k_full<<<dim3(B_, 4), 256, 0, stream>>>(CC, w1, w2, AG1, AG2);
  k_maxpool<<<dim3(B_, 2, 2), 512, 0, stream>>>(CC, w3, w4, AG1, AG2);
  k_alpha<<<dim3(B_, 2), 256, 0, stream>>>(CC, ALPH);
  k_att<<<dim3(B_, 4), 256, 0, stream>>>(CC, ALPH, w5, w6, w7, w8, AG1, AG2);
  gemm_abt<8 * L_><<<dim3(64, 4, 4), 512, 0, stream>>>(AG1, AG2, awih_f, awih_b, ab_f, ab_b,
                                                       XG, B_ * S_, G4);
  k_lstm<<<dim3(B_, 4), 512, 0, stream>>>(XG, awhh_f, awhh_b, CC);
  k_final<<<dim3(B_), 256, 0, stream>>>(CC, pW1, pb1, pW2, pb2, (float*)d_out);
}

// Round 15
// 584.502 us; speedup vs baseline: 1.0993x; 1.0486x over previous
//
#include <hip/hip_runtime.h>
#include <math.h>

// ---------------- problem constants ----------------
#define B_  64
#define S_  128
#define H_  128
#define D_  300
#define L_  20
#define G4  512                 // 4*H
#define SH  (S_*H_)             // 16384
#define BSH ((size_t)B_*SH)     // 1048576
#define EPSV 1e-8f

typedef __attribute__((ext_vector_type(8))) short bshort8;   // 8 bf16 (4 VGPR)
typedef __attribute__((ext_vector_type(4))) float f32x4;     // MFMA C/D

// monotonic float<->uint mapping for atomicMax on floats (handles negatives)
__device__ __forceinline__ unsigned fmap(float f){
  unsigned u = __float_as_uint(f);
  return (u & 0x80000000u) ? ~u : (u | 0x80000000u);
}
__device__ __forceinline__ float funmap(unsigned u){
  return __uint_as_float((u & 0x80000000u) ? (u & 0x7fffffffu) : ~u);
}
// NaN-safe fast activations (__expf; gates here are O(1), err ~1e-6).
// Verified numerically safe: R11-R14 passes with unchanged absmax.
__device__ __forceinline__ float fsigm(float x){ return 1.f/(1.f+__expf(-x)); }
__device__ __forceinline__ float ftanh(float x){ return 1.f - 2.f/(__expf(2.f*x)+1.f); }
__device__ __forceinline__ float dot4(float4 a, float4 b){
  return a.x*b.x + a.y*b.y + a.z*b.z + a.w*b.w;
}
// wave-uniform broadcast of lane k's value (SGPR), no LDS pipe
__device__ __forceinline__ float blane(float v, int k){
  return __int_as_float(__builtin_amdgcn_readlane(__float_as_int(v), k));
}
// fp32 -> bf16 round-to-nearest-even
__device__ __forceinline__ unsigned short f2bf(float f){
  unsigned u = __float_as_uint(f);
  unsigned r = u + 0x7fffu + ((u >> 16) & 1u);
  return (unsigned short)(r >> 16);
}
__device__ __forceinline__ float bf2f(unsigned short us){
  return __uint_as_float(((unsigned)us) << 16);
}
// XOR swizzles: row-major [row][cols], float4-index XOR'd with (row>>3)
__device__ __forceinline__ int swz64(int row, int h){   // 64 cols
  return (row << 6) + ((((h >> 2) ^ ((row >> 3) & 15)) << 2) | (h & 3));
}
__device__ __forceinline__ int swz128(int row, int h){  // 128 cols
  return (row << 7) + ((((h >> 2) ^ ((row >> 3) & 15)) << 2) | (h & 3));
}
// bf16 LDS swizzle: row-major [128 rows][128 h] halfwords; 16B slot XOR row&15
__device__ __forceinline__ int bswz(int row, int slot){  // slot = h>>3
  return (row << 7) + (((slot ^ (row & 15)) << 3));
}
// split fp32 -> (hi,lo) bf16 packs: 8 floats -> 2x int4 (8 bf16 each)
__device__ __forceinline__ void cvt8(float4 a0, float4 a1, int4& hi, int4& lo){
  float v[8] = {a0.x, a0.y, a0.z, a0.w, a1.x, a1.y, a1.z, a1.w};
  unsigned short h[8], l[8];
  #pragma unroll
  for (int i = 0; i < 8; i++) {
    h[i] = f2bf(v[i]);
    float d = v[i] - bf2f(h[i]);
    l[i] = f2bf(d);
  }
  hi = make_int4((unsigned)h[0] | ((unsigned)h[1] << 16), (unsigned)h[2] | ((unsigned)h[3] << 16),
                 (unsigned)h[4] | ((unsigned)h[5] << 16), (unsigned)h[6] | ((unsigned)h[7] << 16));
  lo = make_int4((unsigned)l[0] | ((unsigned)l[1] << 16), (unsigned)l[2] | ((unsigned)l[3] << 16),
                 (unsigned)l[4] | ((unsigned)l[5] << 16), (unsigned)l[6] | ((unsigned)l[7] << 16));
}

// ---------------- GEMM (split-bf16 MFMA): C = A(M,K) * W(N,K)^T + bias ----
// fp32 emulated as hi+lo bf16; C = Ah*Wh + Ah*Wl + Al*Wh (lo*lo dropped,
// rel err ~2^-17). 128x128 tile, 8 waves as 4(M)x2(N) grid of 16x16 MFMA
// tiles per wave, BK=32.
// GATHER=true (R15): A-rows come straight from the embedding table via
// token indices (row fixed per staging thread -> pointer hoisted). This
// replaces the separate k_embed kernel and the X1/X2 round-trip.
template<int K, bool GATHER>
__global__ __launch_bounds__(512, 1) void gemm_abt(
    const float* __restrict__ A0, const float* __restrict__ A1,
    const int* __restrict__ idxP, const int* __restrict__ idxH,
    const float* __restrict__ emb,
    const float* __restrict__ W0, const float* __restrict__ W1,
    const float* __restrict__ b0, const float* __restrict__ b1,
    float* __restrict__ Cbase, int M, int N)
{
  int q = blockIdx.z;
  const float* W = (q & 1) ? W1 : W0;
  const float* bias = (q & 1) ? b1 : b0;
  float* Cm = Cbase + (size_t)q * M * N;

  __shared__ __align__(16) short AsH[128 * 32];
  __shared__ __align__(16) short AsL[128 * 32];
  __shared__ __align__(16) short WsH[128 * 32];
  __shared__ __align__(16) short WsL[128 * 32];

  int t = threadIdx.x;
  int w = t >> 6, lane = t & 63;
  int r = lane & 15, g = lane >> 4;
  int m0 = blockIdx.x * 128, n0 = blockIdx.y * 128;
  int mbase = (w & 1) * 64;        // 4 m-tiles of 16
  int nbase = (w >> 1) * 32;       // 2 n-tiles of 16

  f32x4 acc[4][2];
  #pragma unroll
  for (int i = 0; i < 4; i++)
    #pragma unroll
    for (int j = 0; j < 2; j++) acc[i][j] = (f32x4){0.f, 0.f, 0.f, 0.f};

  int srow = t >> 2, skc = t & 3;                     // staging: row, k-chunk
  int soff = srow * 32 + ((skc ^ ((srow >> 1) & 3)) << 3);

  const float* arow;
  if (GATHER) {
    const int* idx = (q >> 1) ? idxH : idxP;
    arow = emb + (size_t)idx[m0 + srow] * K;          // emb rows 16B-aligned
  } else {
    arow = ((q >> 1) ? A1 : A0) + (size_t)(m0 + srow) * K;
  }
  const float* wrow = W + (size_t)(n0 + srow) * K;

  #pragma unroll 1
  for (int k0 = 0; k0 < K; k0 += 32) {
    {
      int gk = k0 + (skc << 3);
      float4 z = make_float4(0.f, 0.f, 0.f, 0.f);
      float4 a0v = z, a1v = z, w0v = z, w1v = z;
      if (gk < K) {
        a0v = *(const float4*)&arow[gk];
        w0v = *(const float4*)&wrow[gk];
      }
      if (gk + 4 < K) {
        a1v = *(const float4*)&arow[gk + 4];
        w1v = *(const float4*)&wrow[gk + 4];
      }
      int4 hi, lo;
      cvt8(a0v, a1v, hi, lo);
      *(int4*)&AsH[soff] = hi; *(int4*)&AsL[soff] = lo;
      cvt8(w0v, w1v, hi, lo);
      *(int4*)&WsH[soff] = hi; *(int4*)&WsL[soff] = lo;
    }
    __syncthreads();
    bshort8 ah[4], al[4], bh[2], bl[2];
    #pragma unroll
    for (int i = 0; i < 4; i++) {
      int R = mbase + i * 16 + r;
      int off = R * 32 + ((g ^ ((R >> 1) & 3)) << 3);
      ah[i] = *(const bshort8*)&AsH[off];
      al[i] = *(const bshort8*)&AsL[off];
    }
    #pragma unroll
    for (int j = 0; j < 2; j++) {
      int R = nbase + j * 16 + r;
      int off = R * 32 + ((g ^ ((R >> 1) & 3)) << 3);
      bh[j] = *(const bshort8*)&WsH[off];
      bl[j] = *(const bshort8*)&WsL[off];
    }
    #pragma unroll
    for (int i = 0; i < 4; i++)
      #pragma unroll
      for (int j = 0; j < 2; j++) {
        acc[i][j] = __builtin_amdgcn_mfma_f32_16x16x32_bf16(ah[i], bh[j], acc[i][j], 0, 0, 0);
        acc[i][j] = __builtin_amdgcn_mfma_f32_16x16x32_bf16(ah[i], bl[j], acc[i][j], 0, 0, 0);
        acc[i][j] = __builtin_amdgcn_mfma_f32_16x16x32_bf16(al[i], bh[j], acc[i][j], 0, 0, 0);
      }
    __syncthreads();
  }
  // epilogue: C/D layout col=lane&15, row=(lane>>4)*4+reg (HW-verified)
  #pragma unroll
  for (int j = 0; j < 2; j++) {
    int gcol = n0 + nbase + j * 16 + r;
    float bv = bias[gcol];
    #pragma unroll
    for (int i = 0; i < 4; i++) {
      #pragma unroll
      for (int rg = 0; rg < 4; rg++) {
        int grow = m0 + mbase + i * 16 + g * 4 + rg;
        Cm[(size_t)grow * N + gcol] = acc[i][j][rg] + bv;
      }
    }
  }
}

// ---------------- LSTM scan ----------------
// At its structural floor (~156us/launch) after 6 probes: gate-pair dot
// (64 readlane + 128 FMA), 2-wave fast activation, 2 barriers/step.
__global__ __launch_bounds__(512, 1) void k_lstm(const float* __restrict__ xg,
    const float* __restrict__ whhF, const float* __restrict__ whhB,
    float* __restrict__ hs)
{
  int b = blockIdx.x, q = blockIdx.y, dir = q & 1;
  const float* whh = dir ? whhB : whhF;
  const float* xgq = xg + ((size_t)(q * B_ + b)) * (S_ * G4);
  float* out = hs + ((size_t)(q * B_ + b)) * SH;
  int t = threadIdx.x;
  int j = t & 255;                 // gate pair (j, j+256)
  int kh = t >> 8;                 // k-half (wave-uniform: waves 0-3 / 4-7)
  int lane = t & 63;

  float2 w2[64];                   // w2[k] = (whh[j][kh*64+k], whh[j+256][kh*64+k])
  {
    const float* wr0 = whh + (size_t)j * 128 + kh * 64;
    const float* wr1 = whh + (size_t)(j + 256) * 128 + kh * 64;
    #pragma unroll
    for (int k = 0; k < 64; k += 4) {
      float4 v0 = *(const float4*)(wr0 + k);
      float4 v1 = *(const float4*)(wr1 + k);
      w2[k]     = make_float2(v0.x, v1.x);
      w2[k + 1] = make_float2(v0.y, v1.y);
      w2[k + 2] = make_float2(v0.z, v1.z);
      w2[k + 3] = make_float2(v0.w, v1.w);
    }
  }
  __shared__ float hsm[128];
  __shared__ float csm[128];
  __shared__ float gsm[2][512];    // [khalf][gate]
  if (t < 128) { hsm[t] = 0.f; csm[t] = 0.f; }
  __syncthreads();

  float hreg = 0.f;                // wave-replicated h[kh*64 + lane]
  float xn0 = 0.f, xn1 = 0.f;
  if (kh == 0) {
    int t0 = dir ? (S_ - 1) : 0;
    xn0 = xgq[(size_t)t0 * G4 + j];
    xn1 = xgq[(size_t)t0 * G4 + j + 256];
  }

  for (int st = 0; st < S_; st++) {
    int tt = dir ? (S_ - 1 - st) : st;
    float x0 = xn0, x1 = xn1;
    if (kh == 0) {                  // wave-uniform branch: prefetch next step
      int stn = (st + 1 < S_) ? st + 1 : st;
      int ttn = dir ? (S_ - 1 - stn) : stn;
      xn0 = xgq[(size_t)ttn * G4 + j];
      xn1 = xgq[(size_t)ttn * G4 + j + 256];
    }
    // dot: 4 chains x 2 gates; each blane feeds two FMAs
    float a0x = (kh == 0) ? x0 : 0.f, a0y = (kh == 0) ? x1 : 0.f;
    float a1x = 0.f, a1y = 0.f, a2x = 0.f, a2y = 0.f, a3x = 0.f, a3y = 0.f;
    #pragma unroll
    for (int k = 0; k < 64; k += 4) {
      float s0 = blane(hreg, k);
      float s1 = blane(hreg, k + 1);
      float s2 = blane(hreg, k + 2);
      float s3 = blane(hreg, k + 3);
      a0x += w2[k].x * s0;     a0y += w2[k].y * s0;
      a1x += w2[k + 1].x * s1; a1y += w2[k + 1].y * s1;
      a2x += w2[k + 2].x * s2; a2y += w2[k + 2].y * s2;
      a3x += w2[k + 3].x * s3; a3y += w2[k + 3].y * s3;
    }
    gsm[kh][j]       = (a0x + a1x) + (a2x + a3x);
    gsm[kh][j + 256] = (a0y + a1y) + (a2y + a3y);
    __syncthreads();
    if (t < 128) {                  // 2-wave activation, c/h in LDS
      float gi = gsm[0][t]       + gsm[1][t];
      float gf = gsm[0][128 + t] + gsm[1][128 + t];
      float gg = gsm[0][256 + t] + gsm[1][256 + t];
      float go = gsm[0][384 + t] + gsm[1][384 + t];
      float ig = fsigm(gi);
      float fg = fsigm(gf);
      float gv = ftanh(gg);
      float og = fsigm(go);
      float c = fg * csm[t] + ig * gv;
      float hn = og * ftanh(c);
      csm[t] = c; hsm[t] = hn;
      out[(size_t)tt * H_ + t] = hn;
    }
    __syncthreads();
    hreg = hsm[kh * 64 + lane];
  }
}

// ---------------- maxpool matching (bf16 MFMA) ----------------
__global__ __launch_bounds__(512, 1) void k_maxpool(const float* __restrict__ C,
    const float* __restrict__ w3, const float* __restrict__ w4,
    float* __restrict__ ag1, float* __restrict__ ag2)
{
  int b = blockIdx.x, dir = blockIdx.y, lh = blockIdx.z;
  const float* p1 = C + (size_t)(0 + dir) * BSH + (size_t)b * SH;
  const float* p2 = C + (size_t)(2 + dir) * BSH + (size_t)b * SH;
  const float* w = dir ? w4 : w3;

  __shared__ __align__(16) short P1b[128 * 128];
  __shared__ __align__(16) short P2b[128 * 128];
  __shared__ __align__(16) short Ab[128 * 128];
  __shared__ float w2s[128 * 10];
  __shared__ float n1s[128], n2s[128];
  __shared__ unsigned mx2u[128];

  int t = threadIdx.x;
  int wv = t >> 6, lane = t & 63;
  int g = lane >> 4, col = lane & 15;

  for (int i = t; i < 8192; i += 512) {
    int row = i >> 6, hp = i & 63;
    int phys = bswz(row, hp >> 2) + ((hp & 3) << 1);
    float2 v1 = *(const float2*)&p1[(row << 7) + (hp << 1)];
    float2 v2 = *(const float2*)&p2[(row << 7) + (hp << 1)];
    *(unsigned*)&P1b[phys] = (unsigned)f2bf(v1.x) | ((unsigned)f2bf(v1.y) << 16);
    *(unsigned*)&P2b[phys] = (unsigned)f2bf(v2.x) | ((unsigned)f2bf(v2.y) << 16);
  }
  for (int i = t; i < 128 * 10; i += 512) {
    int hh = i / 10, lq = i % 10;
    float wv_ = w[hh * L_ + lh * 10 + lq];
    w2s[i] = wv_ * wv_;
  }
  __syncthreads();

  #pragma unroll 1
  for (int lq = 0; lq < 10; lq++) {
    int lout = lh * 10 + lq;
    for (int i = t; i < 8192; i += 512) {
      int row = i >> 6, hp = i & 63;
      int phys = bswz(row, hp >> 2) + ((hp & 3) << 1);
      unsigned u = *(const unsigned*)&P1b[phys];
      float lo = bf2f((unsigned short)(u & 0xffffu)) * w2s[(hp << 1) * 10 + lq];
      float hi = bf2f((unsigned short)(u >> 16))     * w2s[((hp << 1) + 1) * 10 + lq];
      *(unsigned*)&Ab[phys] = (unsigned)f2bf(lo) | ((unsigned)f2bf(hi) << 16);
    }
    {
      int s = t >> 2, part = t & 3;
      float s1 = 0.f, s2 = 0.f;
      #pragma unroll 1
      for (int hp = part * 16; hp < part * 16 + 16; hp++) {
        int phys = bswz(s, hp >> 2) + ((hp & 3) << 1);
        unsigned u1 = *(const unsigned*)&P1b[phys];
        unsigned u2 = *(const unsigned*)&P2b[phys];
        float wlo = w2s[(hp << 1) * 10 + lq];
        float whi = w2s[((hp << 1) + 1) * 10 + lq];
        float a = bf2f((unsigned short)(u1 & 0xffffu)), bb = bf2f((unsigned short)(u1 >> 16));
        float c2 = bf2f((unsigned short)(u2 & 0xffffu)), d2 = bf2f((unsigned short)(u2 >> 16));
        s1 += a * a * wlo + bb * bb * whi;
        s2 += c2 * c2 * wlo + d2 * d2 * whi;
      }
      s1 += __shfl_xor(s1, 1, 64); s1 += __shfl_xor(s1, 2, 64);
      s2 += __shfl_xor(s2, 1, 64); s2 += __shfl_xor(s2, 2, 64);
      if (part == 0) { n1s[s] = sqrtf(s1); n2s[s] = sqrtf(s2); }
    }
    if (t < 128) mx2u[t] = fmap(-3.4e38f);
    __syncthreads();

    {
      int mrow = (wv << 4) + col;
      f32x4 acc0 = {0,0,0,0}, acc1 = {0,0,0,0}, acc2 = {0,0,0,0}, acc3 = {0,0,0,0};
      f32x4 acc4 = {0,0,0,0}, acc5 = {0,0,0,0}, acc6 = {0,0,0,0}, acc7 = {0,0,0,0};
      #pragma unroll 1
      for (int k0 = 0; k0 < 128; k0 += 32) {
        int slot = ((k0 >> 3) + g) ^ col;
        bshort8 av = *(const bshort8*)&Ab[(mrow << 7) + (slot << 3)];
        bshort8 bv0 = *(const bshort8*)&P2b[((0 << 4) + col << 7) + (slot << 3)];
        bshort8 bv1 = *(const bshort8*)&P2b[(((1 << 4) + col) << 7) + (slot << 3)];
        bshort8 bv2 = *(const bshort8*)&P2b[(((2 << 4) + col) << 7) + (slot << 3)];
        bshort8 bv3 = *(const bshort8*)&P2b[(((3 << 4) + col) << 7) + (slot << 3)];
        bshort8 bv4 = *(const bshort8*)&P2b[(((4 << 4) + col) << 7) + (slot << 3)];
        bshort8 bv5 = *(const bshort8*)&P2b[(((5 << 4) + col) << 7) + (slot << 3)];
        bshort8 bv6 = *(const bshort8*)&P2b[(((6 << 4) + col) << 7) + (slot << 3)];
        bshort8 bv7 = *(const bshort8*)&P2b[(((7 << 4) + col) << 7) + (slot << 3)];
        acc0 = __builtin_amdgcn_mfma_f32_16x16x32_bf16(av, bv0, acc0, 0, 0, 0);
        acc1 = __builtin_amdgcn_mfma_f32_16x16x32_bf16(av, bv1, acc1, 0, 0, 0);
        acc2 = __builtin_amdgcn_mfma_f32_16x16x32_bf16(av, bv2, acc2, 0, 0, 0);
        acc3 = __builtin_amdgcn_mfma_f32_16x16x32_bf16(av, bv3, acc3, 0, 0, 0);
        acc4 = __builtin_amdgcn_mfma_f32_16x16x32_bf16(av, bv4, acc4, 0, 0, 0);
        acc5 = __builtin_amdgcn_mfma_f32_16x16x32_bf16(av, bv5, acc5, 0, 0, 0);
        acc6 = __builtin_amdgcn_mfma_f32_16x16x32_bf16(av, bv6, acc6, 0, 0, 0);
        acc7 = __builtin_amdgcn_mfma_f32_16x16x32_bf16(av, bv7, acc7, 0, 0, 0);
      }
      float n1v[4];
      #pragma unroll
      for (int r = 0; r < 4; r++) n1v[r] = n1s[(wv << 4) + (g << 2) + r];
      float rm[4] = {-3.4e38f, -3.4e38f, -3.4e38f, -3.4e38f};
      float cm[8];
      f32x4 accs[8] = {acc0, acc1, acc2, acc3, acc4, acc5, acc6, acc7};
      #pragma unroll
      for (int c = 0; c < 8; c++) {
        float n2v = n2s[(c << 4) + col];
        float cmx = -3.4e38f;
        #pragma unroll
        for (int r = 0; r < 4; r++) {
          float deno = n1v[r] * n2v;
          float cs = accs[c][r] / (deno > EPSV ? deno : EPSV);
          rm[r] = fmaxf(rm[r], cs);
          cmx = fmaxf(cmx, cs);
        }
        cm[c] = cmx;
      }
      #pragma unroll
      for (int m = 1; m < 16; m <<= 1)
        #pragma unroll
        for (int r = 0; r < 4; r++) rm[r] = fmaxf(rm[r], __shfl_xor(rm[r], m, 64));
      if (col == 0) {
        #pragma unroll
        for (int r = 0; r < 4; r++) {
          int srow = (wv << 4) + (g << 2) + r;
          ag1[(size_t)b * S_ * 160 + (size_t)srow * 160 + 40 + dir * L_ + lout] = rm[r];
        }
      }
      #pragma unroll
      for (int c = 0; c < 8; c++) {
        cm[c] = fmaxf(cm[c], __shfl_xor(cm[c], 16, 64));
        cm[c] = fmaxf(cm[c], __shfl_xor(cm[c], 32, 64));
      }
      if (lane < 16) {
        #pragma unroll
        for (int c = 0; c < 8; c++) atomicMax(&mx2u[(c << 4) + lane], fmap(cm[c]));
      }
    }
    __syncthreads();
    if (t < 128)
      ag2[(size_t)b * S_ * 160 + (size_t)t * 160 + 40 + dir * L_ + lout] = funmap(mx2u[t]);
    __syncthreads();
  }
}

// ---------------- alpha (plain cosine matrix) ----------------
__global__ __launch_bounds__(256, 1) void k_alpha(const float* __restrict__ C,
                                                  float* __restrict__ alpha)
{
  int b = blockIdx.x, dir = blockIdx.y;
  const float* p1 = C + (size_t)(0 + dir) * BSH + (size_t)b * SH;
  const float* p2 = C + (size_t)(2 + dir) * BSH + (size_t)b * SH;
  __shared__ __align__(16) float a1[128 * 64];
  __shared__ __align__(16) float a2[128 * 64];
  __shared__ float n1p[128], n2p[128];
  int t = threadIdx.x, tx = t & 15, ty = t >> 4;
  float acc[8][8] = {};

  for (int pass = 0; pass < 2; pass++) {
    int h0 = pass << 6;
    for (int i = t; i < 128 * 64; i += 256) {
      int row = i >> 6, hh = i & 63;
      int off = swz64(row, hh);
      a1[off] = p1[(size_t)row * H_ + h0 + hh];
      a2[off] = p2[(size_t)row * H_ + h0 + hh];
    }
    __syncthreads();
    {
      int r = t & 127;
      const float* a = (t < 128) ? a1 : a2;
      float s = 0.f;
      #pragma unroll 1
      for (int f = 0; f < 16; f++) {
        float4 v = *(const float4*)&a[(r << 6) + ((f ^ ((r >> 3) & 15)) << 2)];
        s += dot4(v, v);
      }
      float* np = (t < 128) ? n1p : n2p;
      if (pass == 0) np[r] = s; else np[r] += s;
    }
    #pragma unroll 1
    for (int f = 0; f < 16; f++) {
      int cx = ((f ^ ty) << 2);
      int cy = ((f ^ tx) << 2);
      float4 x[8], y[8];
      #pragma unroll
      for (int i = 0; i < 8; i++) x[i] = *(const float4*)&a1[((8 * ty + i) << 6) + cx];
      #pragma unroll
      for (int j = 0; j < 8; j++) y[j] = *(const float4*)&a2[((8 * tx + j) << 6) + cy];
      #pragma unroll
      for (int i = 0; i < 8; i++)
        #pragma unroll
        for (int j = 0; j < 8; j++) acc[i][j] += dot4(x[i], y[j]);
    }
    __syncthreads();
  }
  float inv1[8], inv2[8];
  #pragma unroll
  for (int i = 0; i < 8; i++) inv1[i] = 1.f / fmaxf(sqrtf(n1p[8 * ty + i]), EPSV);
  #pragma unroll
  for (int j = 0; j < 8; j++) inv2[j] = 1.f / fmaxf(sqrtf(n2p[8 * tx + j]), EPSV);
  float* outp = alpha + ((size_t)dir * B_ + b) * SH;
  #pragma unroll
  for (int i = 0; i < 8; i++) {
    int ss = 8 * ty + i;
    float s1 = inv1[i];
    float4 o0 = make_float4(acc[i][0] * s1 * inv2[0], acc[i][1] * s1 * inv2[1],
                            acc[i][2] * s1 * inv2[2], acc[i][3] * s1 * inv2[3]);
    float4 o1 = make_float4(acc[i][4] * s1 * inv2[4], acc[i][5] * s1 * inv2[5],
                            acc[i][6] * s1 * inv2[6], acc[i][7] * s1 * inv2[7]);
    *(float4*)&outp[(size_t)ss * S_ + 8 * tx] = o0;
    *(float4*)&outp[(size_t)ss * S_ + 8 * tx + 4] = o1;
  }
}

// ---------------- attentive matching (+ fused full matching, R15) --------
__global__ __launch_bounds__(256, 1) void k_att(const float* __restrict__ C,
    const float* __restrict__ alpha,
    const float* __restrict__ w5, const float* __restrict__ w6,
    const float* __restrict__ w7, const float* __restrict__ w8,
    const float* __restrict__ w1, const float* __restrict__ w2,
    float* __restrict__ ag1, float* __restrict__ ag2)
{
  int b = blockIdx.x, q = blockIdx.y, dir = q & 1;
  const float* p1  = C + (size_t)q * BSH + (size_t)b * SH;
  const float* m2g = C + (size_t)((q + 2) & 3) * BSH + (size_t)b * SH;
  const float* wa = dir ? w6 : w5;
  const float* wm = dir ? w8 : w7;
  const float* ain = alpha + ((size_t)dir * B_ + b) * SH;
  float* out = (q < 2 ? ag1 : ag2) + (size_t)b * S_ * 160;
  bool tr = (q >= 2);

  __shared__ __align__(16) float A[128 * 128];
  __shared__ __align__(16) float M2T[128 * 128];
  __shared__ __align__(16) float waT[20 * 128];
  __shared__ __align__(16) float wmT[20 * 128];
  __shared__ float rowsum[128];
  __shared__ int   midx[128];
  int t = threadIdx.x, tx = t & 15, ty = t >> 4;

  for (int i = t; i < SH; i += 256) {
    int r = i >> 7, c = i & 127;
    float av = ain[i];
    if (tr) A[swz128(c, r)] = av; else A[swz128(r, c)] = av;
    M2T[swz128(c, r)] = m2g[i];
  }
  for (int i = t; i < H_ * L_; i += 256) {
    int hh = i / L_, l = i % L_;
    float v = wa[i]; waT[l * 128 + hh] = v * v;
    float u = wm[i]; wmT[l * 128 + hh] = u * u;
  }
  __syncthreads();

  if (t < 128) {
    float sum = 0.f, best = -3.4e38f; int bi = 0;
    #pragma unroll 1
    for (int f = 0; f < 32; f++) {
      float4 v = *(const float4*)&A[(t << 7) + (((f ^ ((t >> 3) & 15)) & 31) << 2)];
      sum += v.x + v.y + v.z + v.w;
      int k = f << 2;
      if (v.x > best) { best = v.x; bi = k; }
      if (v.y > best) { best = v.y; bi = k + 1; }
      if (v.z > best) { best = v.z; bi = k + 2; }
      if (v.w > best) { best = v.w; bi = k + 3; }
    }
    rowsum[t] = sum; midx[t] = bi;
  }
  __syncthreads();

  float acc[8][8] = {};
  #pragma unroll 1
  for (int f = 0; f < 32; f++) {
    int cx = (((f ^ ty) & 31) << 2);
    int cy = (((f ^ tx) & 31) << 2);
    float4 x[8], y[8];
    #pragma unroll
    for (int i = 0; i < 8; i++) x[i] = *(const float4*)&A[((8 * ty + i) << 7) + cx];
    #pragma unroll
    for (int j = 0; j < 8; j++) y[j] = *(const float4*)&M2T[((8 * tx + j) << 7) + cy];
    #pragma unroll
    for (int i = 0; i < 8; i++)
      #pragma unroll
      for (int j = 0; j < 8; j++) acc[i][j] += dot4(x[i], y[j]);
  }
  __syncthreads();
  {
    float rinv[8];
    #pragma unroll
    for (int i = 0; i < 8; i++) rinv[i] = 1.f / rowsum[8 * ty + i];
    #pragma unroll
    for (int i = 0; i < 8; i++) {
      int row = 8 * ty + i;
      int f0 = (2 * tx) ^ ((row >> 3) & 15);
      int f1 = (2 * tx + 1) ^ ((row >> 3) & 15);
      float4 o0 = make_float4(acc[i][0] * rinv[i], acc[i][1] * rinv[i],
                              acc[i][2] * rinv[i], acc[i][3] * rinv[i]);
      float4 o1 = make_float4(acc[i][4] * rinv[i], acc[i][5] * rinv[i],
                              acc[i][6] * rinv[i], acc[i][7] * rinv[i]);
      *(float4*)&A[(row << 7) + (f0 << 2)] = o0;
      *(float4*)&A[(row << 7) + (f1 << 2)] = o1;
    }
  }
  __syncthreads();

  {
    int s = t >> 1, l0 = (t & 1) * 10;
    int mi = midx[s];
    const float* m2r = m2g + (size_t)mi * H_;
    const float* p1r = p1 + (size_t)s * H_;
    float dA[10] = {}, nA[10] = {}, bA[10] = {};
    float dM[10] = {}, nM[10] = {}, bM[10] = {};
    #pragma unroll 1
    for (int f = 0; f < 32; f++) {
      float4 pv = *(const float4*)&p1r[f << 2];
      float4 mv = *(const float4*)&m2r[f << 2];
      float4 av = *(const float4*)&A[(s << 7) + (((f ^ ((s >> 3) & 15)) & 31) << 2)];
      float4 ap = make_float4(av.x*pv.x, av.y*pv.y, av.z*pv.z, av.w*pv.w);
      float4 a2 = make_float4(av.x*av.x, av.y*av.y, av.z*av.z, av.w*av.w);
      float4 p2 = make_float4(pv.x*pv.x, pv.y*pv.y, pv.z*pv.z, pv.w*pv.w);
      float4 mp = make_float4(mv.x*pv.x, mv.y*pv.y, mv.z*pv.z, mv.w*pv.w);
      float4 m2 = make_float4(mv.x*mv.x, mv.y*mv.y, mv.z*mv.z, mv.w*mv.w);
      #pragma unroll
      for (int l = 0; l < 10; l++) {
        float4 wv = *(const float4*)&waT[(l0 + l) * 128 + (f << 2)];
        dA[l] += dot4(ap, wv); nA[l] += dot4(a2, wv); bA[l] += dot4(p2, wv);
        float4 uv = *(const float4*)&wmT[(l0 + l) * 128 + (f << 2)];
        dM[l] += dot4(mp, uv); nM[l] += dot4(m2, uv); bM[l] += dot4(p2, uv);
      }
    }
    #pragma unroll
    for (int l = 0; l < 10; l++) {
      int ll = l0 + l;
      out[(size_t)s * 160 + 80  + dir * L_ + ll] =
          dA[l] / (fmaxf(sqrtf(nA[l]), EPSV) * fmaxf(sqrtf(bA[l]), EPSV));
      out[(size_t)s * 160 + 120 + dir * L_ + ll] =
          dM[l] / (fmaxf(sqrtf(nM[l]), EPSV) * fmaxf(sqrtf(bM[l]), EPSV));
    }
  }

  // ---- fused full matching (cols 0..39): thread = (s, l-half) ----
  // Same math/accumulation order as the old k_full; reads from global
  // (L2-hot). p2last = row S-1 of m2g. Saves one kernel launch.
  {
    int s = t >> 1, l0f = (t & 1) * 10;
    const float* wf = dir ? w2 : w1;
    const float* p1r = p1 + (size_t)s * H_;
    const float* p2l = m2g + (size_t)(S_ - 1) * H_;
    float dF[10] = {}, n1F[10] = {}, n2F[10] = {};
    #pragma unroll 1
    for (int f = 0; f < 32; f++) {
      float4 pv = *(const float4*)&p1r[f << 2];
      float4 qv = *(const float4*)&p2l[f << 2];
      #pragma unroll
      for (int l = 0; l < 10; l++) {
        int ll = l0f + l;
        float wa0 = wf[(f * 4 + 0) * L_ + ll]; wa0 *= wa0;
        float wa1 = wf[(f * 4 + 1) * L_ + ll]; wa1 *= wa1;
        float wa2 = wf[(f * 4 + 2) * L_ + ll]; wa2 *= wa2;
        float wa3 = wf[(f * 4 + 3) * L_ + ll]; wa3 *= wa3;
        dF[l]  += pv.x*qv.x*wa0 + pv.y*qv.y*wa1 + pv.z*qv.z*wa2 + pv.w*qv.w*wa3;
        n1F[l] += pv.x*pv.x*wa0 + pv.y*pv.y*wa1 + pv.z*pv.z*wa2 + pv.w*pv.w*wa3;
        n2F[l] += qv.x*qv.x*wa0 + qv.y*qv.y*wa1 + qv.z*qv.z*wa2 + qv.w*qv.w*wa3;
      }
    }
    #pragma unroll
    for (int l = 0; l < 10; l++) {
      int ll = l0f + l;
      out[(size_t)s * 160 + dir * L_ + ll] =
          dF[l] / (fmaxf(sqrtf(n1F[l]), EPSV) * fmaxf(sqrtf(n2F[l]), EPSV));
    }
  }
}

// ---------------- final MLP ----------------
__global__ __launch_bounds__(256) void k_final(const float* __restrict__ Cc,
    const float* __restrict__ pW1, const float* __restrict__ pb1,
    const float* __restrict__ pW2, const float* __restrict__ pb2,
    float* __restrict__ out)
{
  int b = blockIdx.x, t = threadIdx.x;
  __shared__ float cat[512];
  __shared__ float hid[256];
  if (t < 128) {
    cat[t]       = Cc[(size_t)(0 * B_ + b) * SH + (size_t)(S_ - 1) * H_ + t];
    cat[128 + t] = Cc[(size_t)(1 * B_ + b) * SH + (size_t)(S_ - 1) * H_ + t];
    cat[256 + t] = Cc[(size_t)(2 * B_ + b) * SH + (size_t)(S_ - 1) * H_ + t];
    cat[384 + t] = Cc[(size_t)(3 * B_ + b) * SH + (size_t)(S_ - 1) * H_ + t];
  }
  __syncthreads();
  float a = pb1[t];
  for (int k = 0; k < 512; k++) a += cat[k] * pW1[(size_t)t * 512 + k];
  hid[t] = fmaxf(a, 0.f);
  __syncthreads();
  if (t < 3) {
    float o = pb2[t];
    for (int k = 0; k < 256; k++) o += hid[k] * pW2[(size_t)t * 256 + k];
    out[(size_t)b * 3 + t] = o;
  }
}

// ---------------- launch ----------------
extern "C" void kernel_launch(void* const* d_in, const int* in_sizes, int n_in,
                              void* d_out, int out_size, void* d_ws, size_t ws_size,
                              hipStream_t stream)
{
  const float* emb    = (const float*)d_in[0];
  const float* cwih_f = (const float*)d_in[1];
  const float* cwhh_f = (const float*)d_in[2];
  const float* cb_f   = (const float*)d_in[3];
  const float* cwih_b = (const float*)d_in[4];
  const float* cwhh_b = (const float*)d_in[5];
  const float* cb_b   = (const float*)d_in[6];
  const float* awih_f = (const float*)d_in[7];
  const float* awhh_f = (const float*)d_in[8];
  const float* ab_f   = (const float*)d_in[9];
  const float* awih_b = (const float*)d_in[10];
  const float* awhh_b = (const float*)d_in[11];
  const float* ab_b   = (const float*)d_in[12];
  const float* pW1    = (const float*)d_in[13];
  const float* pb1    = (const float*)d_in[14];
  const float* pW2    = (const float*)d_in[15];
  const float* pb2    = (const float*)d_in[16];
  const int*   pidx   = (const int*)d_in[17];
  const int*   hidx   = (const int*)d_in[18];
  const float* w1 = (const float*)d_in[19];
  const float* w2 = (const float*)d_in[20];
  const float* w3 = (const float*)d_in[21];
  const float* w4 = (const float*)d_in[22];
  const float* w5 = (const float*)d_in[23];
  const float* w6 = (const float*)d_in[24];
  const float* w7 = (const float*)d_in[25];
  const float* w8 = (const float*)d_in[26];

  float* ws = (float*)d_ws;
  float* XG   = ws;
  float* ALPH = ws + 16777216;                 // former X1 region
  float* AG1  = ws + 16777216 + 2097152;
  float* AG2  = AG1 + (size_t)B_ * S_ * 160;
  float* CC   = ws + 21692416;

  // 1) ctx input projections, gathering A-rows straight from the embedding
  gemm_abt<D_, true><<<dim3(64, 4, 4), 512, 0, stream>>>(
      nullptr, nullptr, pidx, hidx, emb, cwih_f, cwih_b, cb_f, cb_b,
      XG, B_ * S_, G4);
  // 2) ctx BiLSTM scans -> c1f,c1b,c2f,c2b
  k_lstm<<<dim3(B_, 4), 512, 0, stream>>>(XG, cwhh_f, cwhh_b, CC);
  // 3) maxpool matching (cols 40..79)
  k_maxpool<<<dim3(B_, 2, 2), 512, 0, stream>>>(CC, w3, w4, AG1, AG2);
  // 4) attention cosine matrices
  k_alpha<<<dim3(B_, 2), 256, 0, stream>>>(CC, ALPH);
  // 5) attentive + attentive-max + (fused) full matching (cols 0..39, 80..159)
  k_att<<<dim3(B_, 4), 256, 0, stream>>>(CC, ALPH, w5, w6, w7, w8, w1, w2,
                                         AG1, AG2);
  // 6) agg input projections
  gemm_abt<8 * L_, false><<<dim3(64, 4, 4), 512, 0, stream>>>(
      AG1, AG2, nullptr, nullptr, nullptr, awih_f, awih_b, ab_f, ab_b,
      XG, B_ * S_, G4);
  // 7) agg BiLSTM scans
  k_lstm<<<dim3(B_, 4), 512, 0, stream>>>(XG, awhh_f, awhh_b, CC);
  // 8) final MLP
  k_final<<<dim3(B_), 256, 0, stream>>>(CC, pW1, pb1, pW2, pb2, (float*)d_out);
}